// Round 11
// baseline (871.961 us; speedup 1.0000x reference)
//
#include <hip/hip_runtime.h>
#include <hip/hip_bf16.h>
#include <cstddef>

#define TPB 256
#define TPB_BIN 1024
#define NPB 512        // nodes per bucket
#define BSH 9          // log2(NPB)
#define CHUNK 8192     // edges per k_bin1 block

typedef unsigned int u32;

__device__ __forceinline__ float lrelu(float v, float s){ return v > 0.f ? v : s*v; }

__device__ __forceinline__ unsigned short bf16_rne(float f){
    u32 u = __float_as_uint(f);
    u += 0x7FFFu + ((u >> 16) & 1u);
    return (unsigned short)(u >> 16);
}
__device__ __forceinline__ float bf_lo(u32 w){ return __uint_as_float(w << 16); }
__device__ __forceinline__ float bf_hi(u32 w){ return __uint_as_float(w & 0xFFFF0000u); }

// ---------------- K1: h = x @ W_gat; merged 128B node row [a_src x3 | pad | h bf16 x48 | pad] ----------------
__global__ __launch_bounds__(TPB) void k1_embed(
    const float* __restrict__ x, const float* __restrict__ Wg,
    const float* __restrict__ atts, const float* __restrict__ attd,
    u32* __restrict__ hrow, float4* __restrict__ a_dst4, int N)
{
    __shared__ float Ws[32*48];
    __shared__ float As[48], Ad[48];
    for (int i = threadIdx.x; i < 32*48; i += TPB) Ws[i] = Wg[i];
    if (threadIdx.x < 48){ As[threadIdx.x] = atts[threadIdx.x]; Ad[threadIdx.x] = attd[threadIdx.x]; }
    __syncthreads();
    int n = blockIdx.x*TPB + threadIdx.x;
    if (n >= N) return;
    float xr[32];
    const float4* xp = (const float4*)(x + (size_t)n*32);
    #pragma unroll
    for (int i=0;i<8;i++){ float4 v = xp[i]; xr[4*i+0]=v.x; xr[4*i+1]=v.y; xr[4*i+2]=v.z; xr[4*i+3]=v.w; }
    float hv[48];
    #pragma unroll 4
    for (int j=0;j<48;j++){
        float acc = 0.f;
        #pragma unroll
        for (int i=0;i<32;i++) acc = fmaf(xr[i], Ws[i*48+j], acc);
        hv[j] = acc;
    }
    float asv[3], adv[3];
    #pragma unroll
    for (int hh=0;hh<3;hh++){
        float s0=0.f, s1=0.f;
        #pragma unroll
        for (int d=0;d<16;d++){ s0 = fmaf(hv[hh*16+d], As[hh*16+d], s0); s1 = fmaf(hv[hh*16+d], Ad[hh*16+d], s1); }
        asv[hh]=s0; adv[hh]=s1;
    }
    u32 w[24];
    #pragma unroll
    for (int q=0;q<12;q++){
        w[2*q]   = (u32)bf16_rne(hv[4*q+0]) | ((u32)bf16_rne(hv[4*q+1]) << 16);
        w[2*q+1] = (u32)bf16_rne(hv[4*q+2]) | ((u32)bf16_rne(hv[4*q+3]) << 16);
    }
    uint4* hp4 = (uint4*)(hrow + (size_t)n*32);
    hp4[0] = make_uint4(__float_as_uint(asv[0]), __float_as_uint(asv[1]), __float_as_uint(asv[2]), 0u);
    #pragma unroll
    for (int i=0;i<6;i++) hp4[1+i] = make_uint4(w[4*i],w[4*i+1],w[4*i+2],w[4*i+3]);
    hp4[7] = make_uint4(0u,0u,0u,0u);
    a_dst4[n] = make_float4(adv[0],adv[1],adv[2],0.f);
}

// ---------------- k_bin1: chunk -> bucket-grouped block-private staging (1024 threads, wave-scan) ----------------
__global__ __launch_bounds__(TPB_BIN) void k_bin1(
    const int* __restrict__ ei, u32* __restrict__ staging,
    int* __restrict__ chunk_off, int* __restrict__ chunk_cnt,
    int* __restrict__ btot_pad, int E)
{
    __shared__ uint2 stash[CHUNK];
    __shared__ int lcnt[256], lcur[256];
    int t = threadIdx.x;
    int blockStart = blockIdx.x * CHUNK;
    int len = E - blockStart; if (len > CHUNK) len = CHUNK; if (len < 0) len = 0;
    if (t < 256) lcnt[t] = 0;
    __syncthreads();
    for (int i = t; i < len; i += TPB_BIN){
        int s = ei[blockStart + i];
        int d = ei[E + blockStart + i];
        stash[i] = make_uint2((unsigned)s, (unsigned)d);
        atomicAdd(&lcnt[d >> BSH], 1);
    }
    __syncthreads();
    if (t < 256){
        int myc = lcnt[t];
        atomicAdd(&btot_pad[t*16], myc);
        chunk_cnt[blockIdx.x*256 + t] = myc;
    }
    __syncthreads();
    if (t < 64){
        int v0=lcnt[4*t+0], v1=lcnt[4*t+1], v2=lcnt[4*t+2], v3=lcnt[4*t+3];
        int s = v0+v1+v2+v3, tot = s;
        #pragma unroll
        for (int off=1; off<64; off<<=1){ int xch = __shfl_up(s, off); if (t >= off) s += xch; }
        int base = s - tot;
        lcur[4*t+0]=base; lcur[4*t+1]=base+v0; lcur[4*t+2]=base+v0+v1; lcur[4*t+3]=base+v0+v1+v2;
    }
    __syncthreads();
    if (t < 256) chunk_off[blockIdx.x*256 + t] = lcur[t];
    __syncthreads();
    for (int i = t; i < len; i += TPB_BIN){
        uint2 e = stash[i];
        int b = (int)(e.y >> BSH);
        int pos = atomicAdd(&lcur[b], 1);
        staging[blockStart + pos] = e.x | ((e.y & (NPB-1u)) << 17);
    }
}

// ---------------- k_bin2: per-bucket assemble via direct chunk-segment iteration (no binary search) ----------------
__global__ __launch_bounds__(TPB_BIN) void k_bin2(
    const u32* __restrict__ staging,
    const int* __restrict__ chunk_off, const int* __restrict__ chunk_cnt,
    const int* __restrict__ btot_pad, int* __restrict__ rowptr, int* __restrict__ cnt_g,
    int* __restrict__ csr_src, int NCB)
{
    __shared__ int co[256], cl[256];
    __shared__ int lcnt[NPB], lcur[NPB];
    __shared__ int cbs;
    int b = blockIdx.x, t = threadIdx.x;
    if (t < 256){
        co[t] = (t < NCB) ? chunk_off[t*256 + b] : 0;
        cl[t] = (t < NCB) ? chunk_cnt[t*256 + b] : 0;
    }
    if (t < NPB) lcnt[t] = 0;
    if (t < 64){
        int s = 0;
        for (int i=t; i<b; i+=64) s += btot_pad[i*16];
        #pragma unroll
        for (int off=32; off; off>>=1) s += __shfl_xor(s, off);
        if (t == 0) cbs = s;
    }
    __syncthreads();
    int cb = cbs;
    int wv = t >> 6, lane = t & 63;   // 16 waves
    // phase A: count nodes, per-chunk direct iteration (coalesced segment reads)
    for (int c = wv; c < NCB; c += 16){
        int len = cl[c];
        size_t base = (size_t)c*CHUNK + co[c];
        for (int i = lane; i < len; i += 64){
            u32 val = staging[base + i];
            atomicAdd(&lcnt[(val>>17)&(NPB-1u)], 1);
        }
    }
    __syncthreads();
    // wave-scan 512 node counts -> lcur (exclusive)
    if (t < 64){
        int v[8]; int ss = 0;
        #pragma unroll
        for (int k=0;k<8;k++){ v[k] = lcnt[8*t+k]; ss += v[k]; }
        int tot = ss;
        #pragma unroll
        for (int off=1; off<64; off<<=1){ int xch = __shfl_up(ss, off); if (t >= off) ss += xch; }
        int base = ss - tot;
        #pragma unroll
        for (int k=0;k<8;k++){ lcur[8*t+k] = base; base += v[k]; }
    }
    __syncthreads();
    if (t < NPB){ rowptr[b*NPB + t] = cb + lcur[t]; cnt_g[b*NPB + t] = lcnt[t]; }
    __syncthreads();
    // phase C: scatter into bucket-local CSR window (L2-resident)
    for (int c = wv; c < NCB; c += 16){
        int len = cl[c];
        size_t base = (size_t)c*CHUNK + co[c];
        for (int i = lane; i < len; i += 64){
            u32 val = staging[base + i];
            int node = (int)((val>>17)&(NPB-1u));
            int pos = atomicAdd(&lcur[node],1);
            csr_src[cb+pos] = (int)(val & 0x1FFFFu);
        }
    }
}

// ---------------- K_gat (R9 version): wave/node; uniform-trip preloaded-index gather, LDS epilogue, fused BN1 ----------------
__global__ __launch_bounds__(TPB) void k_gat(
    const int* __restrict__ rowptr, const int* __restrict__ cnt, const int* __restrict__ csr_src,
    const u32* __restrict__ hrow, const float* __restrict__ a_dstf,
    const float* __restrict__ b_gat,
    const float* __restrict__ W_ht, const float* __restrict__ b_ht,
    float* __restrict__ out_ht, float* __restrict__ part, int N, int cpx)
{
    __shared__ float Wh[768];
    __shared__ float bg[48], bh[16];
    __shared__ float gl[4][52];
    __shared__ float ls2[4][16];
    for (int i=threadIdx.x;i<768;i+=TPB) Wh[i]=W_ht[i];
    if (threadIdx.x<48) bg[threadIdx.x]=b_gat[threadIdx.x];
    if (threadIdx.x<16) bh[threadIdx.x]=b_ht[threadIdx.x];
    __syncthreads();
    int bid = blockIdx.x;
    int bid2 = (bid & 7)*cpx + (bid >> 3);       // XCD-contiguous swizzle (gridDim % 8 == 0)
    int lane = threadIdx.x & 63;
    int wv = threadIdx.x >> 6;
    int n = bid2*4 + wv;                          // grid = N/4 exactly

    int g = lane>>4, q = lane&15;
    int hq = (q < 12) ? (q >> 2) : (q - 12);
    if (q == 15) hq = 0;
    bool is_msg = (q < 12);
    bool is_z   = (q >= 12 && q < 15);

    float adh   = a_dstf[(size_t)n*4 + hq];
    float asn_h = __uint_as_float(hrow[(size_t)n*32 + hq]);
    float wself = __expf(lrelu(asn_h + adh, 0.2f));

    int rs = rowptr[n];
    int deg = cnt[n];

    float4 acc = make_float4(0.f,0.f,0.f,0.f);
    float zacc = 0.f;

    for (int base = 0; base < deg; base += 64){
        int m = deg - base; if (m > 64) m = 64;           // wave-uniform
        int idx = csr_src[rs + base + (lane < m ? lane : 0)];
        int niter = (m + 15) >> 4;                        // wave-uniform trip count
        for (int i = 0; i < niter; i++){
            int jj = g + (i << 4);                        // lanes jj..jj+12 always in [0,63]
            int s0=__shfl(idx,jj), s1=__shfl(idx,jj+4), s2=__shfl(idx,jj+8), s3=__shfl(idx,jj+12);
            const u32* p0 = hrow + (size_t)s0*32;
            const u32* p1 = hrow + (size_t)s1*32;
            const u32* p2 = hrow + (size_t)s2*32;
            const u32* p3 = hrow + (size_t)s3*32;
            float av0=__uint_as_float(p0[hq]);
            float av1=__uint_as_float(p1[hq]);
            float av2=__uint_as_float(p2[hq]);
            float av3=__uint_as_float(p3[hq]);
            uint2 r0,r1,r2,r3;
            if (is_msg){
                r0=*(const uint2*)(p0+4+2*q); r1=*(const uint2*)(p1+4+2*q);
                r2=*(const uint2*)(p2+4+2*q); r3=*(const uint2*)(p3+4+2*q);
            }
            float w0 = (jj      < m) ? __expf(lrelu(av0+adh,0.2f)) : 0.f;
            float w1 = (jj + 4  < m) ? __expf(lrelu(av1+adh,0.2f)) : 0.f;
            float w2 = (jj + 8  < m) ? __expf(lrelu(av2+adh,0.2f)) : 0.f;
            float w3 = (jj + 12 < m) ? __expf(lrelu(av3+adh,0.2f)) : 0.f;
            if (is_msg){
                acc.x=fmaf(w0,bf_lo(r0.x),acc.x); acc.y=fmaf(w0,bf_hi(r0.x),acc.y);
                acc.z=fmaf(w0,bf_lo(r0.y),acc.z); acc.w=fmaf(w0,bf_hi(r0.y),acc.w);
                acc.x=fmaf(w1,bf_lo(r1.x),acc.x); acc.y=fmaf(w1,bf_hi(r1.x),acc.y);
                acc.z=fmaf(w1,bf_lo(r1.y),acc.z); acc.w=fmaf(w1,bf_hi(r1.y),acc.w);
                acc.x=fmaf(w2,bf_lo(r2.x),acc.x); acc.y=fmaf(w2,bf_hi(r2.x),acc.y);
                acc.z=fmaf(w2,bf_lo(r2.y),acc.z); acc.w=fmaf(w2,bf_hi(r2.y),acc.w);
                acc.x=fmaf(w3,bf_lo(r3.x),acc.x); acc.y=fmaf(w3,bf_hi(r3.x),acc.y);
                acc.z=fmaf(w3,bf_lo(r3.y),acc.z); acc.w=fmaf(w3,bf_hi(r3.y),acc.w);
            } else if (is_z){
                zacc += (w0+w1)+(w2+w3);
            }
        }
    }

    #pragma unroll
    for (int off=16; off<64; off<<=1){
        acc.x += __shfl_xor(acc.x, off); acc.y += __shfl_xor(acc.y, off);
        acc.z += __shfl_xor(acc.z, off); acc.w += __shfl_xor(acc.w, off);
        zacc  += __shfl_xor(zacc,  off);
    }
    float z_mine = __shfl(zacc, 12 + hq) + wself;

    if (g==0 && q<12){
        uint2 hs = *(const uint2*)(hrow + (size_t)n*32 + 4 + 2*q);
        float inv = 1.f / z_mine;
        float4 gq;
        gq.x = (acc.x + wself*bf_lo(hs.x))*inv + bg[4*q+0];
        gq.y = (acc.y + wself*bf_hi(hs.x))*inv + bg[4*q+1];
        gq.z = (acc.z + wself*bf_lo(hs.y))*inv + bg[4*q+2];
        gq.w = (acc.w + wself*bf_hi(hs.y))*inv + bg[4*q+3];
        *(float4*)&gl[wv][4*q] = gq;
    }
    __syncthreads();
    int j16 = lane & 15, pr = lane >> 4;
    float oacc = 0.f;
    const float* gv = &gl[wv][pr*12];
    #pragma unroll
    for (int k=0;k<12;k++) oacc = fmaf(gv[k], Wh[(pr*12+k)*16 + j16], oacc);
    oacc += __shfl_xor(oacc, 16);
    oacc += __shfl_xor(oacc, 32);
    float oval = oacc + bh[j16];
    if (lane < 16){
        out_ht[(size_t)n*16 + lane] = oval;
        ls2[wv][lane] = oval;
    }
    __syncthreads();
    int t = threadIdx.x;
    if (t < 16){
        float s=0.f, qd=0.f;
        #pragma unroll
        for (int w2=0;w2<4;w2++){ float v=ls2[w2][t]; s+=v; qd+=v*v; }
        part[(size_t)bid*32 + t] = s;
        part[(size_t)bid*32 + 16 + t] = qd;
    }
}

// ---------------- k_bnred16: mid-reduce 32768x32 -> 256x32, last block finishes -> bn (one launch) ----------------
__global__ __launch_bounds__(TPB) void k_bnred16(const float* __restrict__ part, float* __restrict__ part2,
                                                 float* __restrict__ bn, int* __restrict__ ctr)
{
    __shared__ float ls[8][32];
    __shared__ int lastf;
    int t = threadIdx.x, b = blockIdx.x;
    int col = t & 31, grp = t >> 5;
    float s = 0.f;
    #pragma unroll
    for (int i=0;i<16;i++){ int r = b*128 + grp*16 + i; s += part[(size_t)r*32 + col]; }
    ls[grp][col] = s; __syncthreads();
    if (t < 32){
        float a = 0.f;
        #pragma unroll
        for (int g=0; g<8; g++) a += ls[g][t];
        part2[(size_t)b*32 + t] = a;
    }
    __threadfence();
    if (t == 0) lastf = (atomicAdd(ctr, 1) == (int)gridDim.x - 1);
    __syncthreads();
    if (lastf){
        __threadfence();
        float s2 = 0.f;
        for (int r=grp; r<256; r+=8) s2 += part2[(size_t)r*32 + col];
        __syncthreads();
        ls[grp][col] = s2; __syncthreads();
        if (t < 32){
            float a = 0.f;
            #pragma unroll
            for (int g=0; g<8; g++) a += ls[g][t];
            bn[t] = a;
        }
    }
}

// ---------------- K5: BN1 apply + GCN matmul + write dinv-prescaled bf16 xws ----------------
__global__ __launch_bounds__(TPB) void k5_bn1_gcnmm(
    const float* __restrict__ out_ht, const float* __restrict__ bn,
    const float* __restrict__ g1, const float* __restrict__ be1,
    const float* __restrict__ W_gcn, const int* __restrict__ cnt,
    float* __restrict__ dinv, uint4* __restrict__ xws, int N)
{
    __shared__ float sc[16], sh[16], Wg[128];
    int t = threadIdx.x;
    if (t < 16){
        float mu  = bn[t]/(float)N;
        float var = bn[16+t]/(float)N - mu*mu;
        float s = rsqrtf(var+1e-5f)*g1[t];
        sc[t]=s; sh[t]=be1[t]-mu*s;
    }
    if (t < 128) Wg[t] = W_gcn[t];
    __syncthreads();
    int n = blockIdx.x*TPB + t;
    if (n >= N) return;
    float v[16];
    const float4* ip = (const float4*)(out_ht + (size_t)n*16);
    #pragma unroll
    for (int q=0;q<4;q++){
        float4 vv = ip[q];
        v[4*q+0]=vv.x*sc[4*q+0]+sh[4*q+0];
        v[4*q+1]=vv.y*sc[4*q+1]+sh[4*q+1];
        v[4*q+2]=vv.z*sc[4*q+2]+sh[4*q+2];
        v[4*q+3]=vv.w*sc[4*q+3]+sh[4*q+3];
    }
    float dv = rsqrtf((float)(cnt[n]+1));
    float o[8];
    #pragma unroll
    for (int k=0;k<8;k++){
        float acc=0.f;
        #pragma unroll
        for (int j=0;j<16;j++) acc = fmaf(v[j], Wg[j*8+k], acc);
        o[k]=acc*dv;
    }
    u32 w0 = (u32)bf16_rne(o[0]) | ((u32)bf16_rne(o[1])<<16);
    u32 w1 = (u32)bf16_rne(o[2]) | ((u32)bf16_rne(o[3])<<16);
    u32 w2 = (u32)bf16_rne(o[4]) | ((u32)bf16_rne(o[5])<<16);
    u32 w3 = (u32)bf16_rne(o[6]) | ((u32)bf16_rne(o[7])<<16);
    xws[n] = make_uint4(w0,w1,w2,w3);
    dinv[n] = dv;
}

// ---------------- K_gcn: gather + fused BN2 partials + last-block BN2 finish ----------------
__global__ __launch_bounds__(TPB) void k_gcn(
    const int* __restrict__ rowptr, const int* __restrict__ cnt, const int* __restrict__ csr_src,
    const float* __restrict__ dinv, const uint4* __restrict__ xws,
    const float* __restrict__ b_gcn, float* __restrict__ gout, float* __restrict__ part,
    float* __restrict__ bn2, int* __restrict__ ctr, int N, int cpx)
{
    __shared__ float ls[16][16];
    __shared__ int lastf;
    int bid = blockIdx.x;
    int bid2 = (bid & 7)*cpx + (bid >> 3);
    int t = threadIdx.x;
    int node = bid2*16 + (t >> 4);
    int sub  = t & 15;
    int grp  = t >> 4;
    float val[8];
    #pragma unroll
    for (int k=0;k<8;k++) val[k]=0.f;
    if (node < N){
        int rs = rowptr[node], re = rs + cnt[node];
        float a0=0.f,a1=0.f,a2=0.f,a3=0.f,a4=0.f,a5=0.f,a6=0.f,a7=0.f;
        for (int j=rs+sub; j<re; j+=16){
            int s = csr_src[j];
            uint4 r = xws[s];
            a0 += bf_lo(r.x); a1 += bf_hi(r.x);
            a2 += bf_lo(r.y); a3 += bf_hi(r.y);
            a4 += bf_lo(r.z); a5 += bf_hi(r.z);
            a6 += bf_lo(r.w); a7 += bf_hi(r.w);
        }
        #pragma unroll
        for (int off=1; off<16; off<<=1){
            a0 += __shfl_xor(a0, off); a1 += __shfl_xor(a1, off);
            a2 += __shfl_xor(a2, off); a3 += __shfl_xor(a3, off);
            a4 += __shfl_xor(a4, off); a5 += __shfl_xor(a5, off);
            a6 += __shfl_xor(a6, off); a7 += __shfl_xor(a7, off);
        }
        if (sub == 0){
            uint4 r = xws[node];
            a0 += bf_lo(r.x); a1 += bf_hi(r.x);
            a2 += bf_lo(r.y); a3 += bf_hi(r.y);
            a4 += bf_lo(r.z); a5 += bf_hi(r.z);
            a6 += bf_lo(r.w); a7 += bf_hi(r.w);
            float dd = dinv[node];
            val[0]=fmaf(dd,a0,b_gcn[0]); val[1]=fmaf(dd,a1,b_gcn[1]);
            val[2]=fmaf(dd,a2,b_gcn[2]); val[3]=fmaf(dd,a3,b_gcn[3]);
            val[4]=fmaf(dd,a4,b_gcn[4]); val[5]=fmaf(dd,a5,b_gcn[5]);
            val[6]=fmaf(dd,a6,b_gcn[6]); val[7]=fmaf(dd,a7,b_gcn[7]);
            float4* op = (float4*)(gout + (size_t)node*8);
            op[0] = make_float4(val[0],val[1],val[2],val[3]);
            op[1] = make_float4(val[4],val[5],val[6],val[7]);
        }
    }
    if (sub == 0){
        #pragma unroll
        for (int k=0;k<8;k++){ ls[grp][k] = val[k]; ls[grp][8+k] = val[k]*val[k]; }
    }
    __syncthreads();
    if (t < 16){
        float s = 0.f;
        #pragma unroll
        for (int g2=0; g2<16; g2++) s += ls[g2][t];
        part[(size_t)bid*16 + t] = s;
    }
    __threadfence();
    if (t == 0) lastf = (atomicAdd(ctr, 1) == (int)gridDim.x - 1);
    __syncthreads();
    if (lastf){
        __threadfence();
        int col = t & 15, g16 = t >> 4;
        float s = 0.f;
        for (int r=g16; r<(int)gridDim.x; r+=16) s += part[(size_t)r*16 + col];
        __syncthreads();
        ls[g16][col] = s; __syncthreads();
        if (t < 16){
            float a = 0.f;
            #pragma unroll
            for (int g2=0; g2<16; g2++) a += ls[g2][t];
            bn2[t] = a;
        }
    }
}

// ---------------- K8: BN2 apply + per-graph dense head ----------------
__global__ __launch_bounds__(TPB) void k8_head(
    const float* __restrict__ gcn, const float* __restrict__ bn2,
    const float* __restrict__ g2, const float* __restrict__ be2,
    const float* __restrict__ W1, const float* __restrict__ b1,
    const float* __restrict__ W2, const float* __restrict__ b2,
    const float* __restrict__ Wt, const float* __restrict__ bt,
    const float* __restrict__ Wmu, const float* __restrict__ bmu,
    const float* __restrict__ Wls, const float* __restrict__ bls,
    float* __restrict__ out, int N, int B)
{
    __shared__ float v[4096];
    __shared__ float red[8][32];
    __shared__ float y1[32], y2[16], y3[64];
    int b = blockIdx.x, t = threadIdx.x;
    float sc[8], sh[8];
    #pragma unroll
    for (int k=0;k<8;k++){
        float mu  = bn2[k]/(float)N;
        float var = bn2[8+k]/(float)N - mu*mu;
        float s = rsqrtf(var+1e-5f)*g2[k];
        sc[k]=s; sh[k]=be2[k]-mu*s;
    }
    const float* src = gcn + (size_t)b*4096;
    for (int i=t;i<4096;i+=TPB){ int k=i&7; v[i]=src[i]*sc[k]+sh[k]; }
    __syncthreads();
    int j = t & 31, c = t >> 5;
    float p = 0.f;
    int base = c*512;
    for (int i=0;i<512;i++) p = fmaf(v[base+i], W1[(size_t)(base+i)*32+j], p);
    red[c][j] = p;
    __syncthreads();
    if (t < 32){
        float a = b1[t];
        #pragma unroll
        for (int cc=0;cc<8;cc++) a += red[cc][t];
        y1[t] = lrelu(a, 0.01f);
    }
    __syncthreads();
    if (t < 16){
        float a = b2[t];
        #pragma unroll
        for (int i=0;i<32;i++) a = fmaf(y1[i], W2[i*16+t], a);
        y2[t] = lrelu(a, 0.01f);
    }
    __syncthreads();
    if (t < 64){
        float a = bt[t];
        #pragma unroll
        for (int i=0;i<16;i++) a = fmaf(y2[i], Wt[i*64+t], a);
        y3[t] = lrelu(a, 0.01f);
    }
    __syncthreads();
    if (t < 64){
        float amu = bmu[t], als = bls[t];
        #pragma unroll
        for (int i=0;i<64;i++){ amu = fmaf(y3[i], Wmu[i*64+t], amu); als = fmaf(y3[i], Wls[i*64+t], als); }
        out[(size_t)b*64 + t] = amu;
        out[(size_t)B*64 + (size_t)b*64 + t] = als;
    }
}

extern "C" void kernel_launch(void* const* d_in, const int* in_sizes, int n_in,
                              void* d_out, int out_size, void* d_ws, size_t ws_size,
                              hipStream_t stream)
{
    const float* x     = (const float*)d_in[0];
    const int*   ei    = (const int*)  d_in[1];
    const float* W_gat = (const float*)d_in[2];
    const float* atts  = (const float*)d_in[3];
    const float* attd  = (const float*)d_in[4];
    const float* b_gat = (const float*)d_in[5];
    const float* W_ht  = (const float*)d_in[6];
    const float* b_ht  = (const float*)d_in[7];
    const float* g1    = (const float*)d_in[8];
    const float* be1   = (const float*)d_in[9];
    const float* W_gcn = (const float*)d_in[10];
    const float* b_gcn = (const float*)d_in[11];
    const float* g2    = (const float*)d_in[12];
    const float* be2   = (const float*)d_in[13];
    const float* W1    = (const float*)d_in[14];
    const float* b1    = (const float*)d_in[15];
    const float* W2    = (const float*)d_in[16];
    const float* b2    = (const float*)d_in[17];
    const float* Wt    = (const float*)d_in[18];
    const float* bt    = (const float*)d_in[19];
    const float* Wmu   = (const float*)d_in[20];
    const float* bmu   = (const float*)d_in[21];
    const float* Wls   = (const float*)d_in[22];
    const float* bls   = (const float*)d_in[23];
    float* out = (float*)d_out;

    const int N = in_sizes[0] / 32;
    const int E = in_sizes[1] / 2;
    const int B = N / 512;
    const int NBUCK = N / NPB;
    const int NCB = (E + CHUNK - 1) / CHUNK;

    char* wsb = (char*)d_ws;
    size_t off = 0;
    auto alloc = [&](size_t bytes){ void* p = wsb + off; off += (bytes + 255) & ~(size_t)255; return p; };
    char*   hreg    = (char*)  alloc((size_t)N*128);     // merged node rows; later xws+gout
    float*  out_ht  = (float*) alloc((size_t)N*16*4);
    float4* a_dst4  = (float4*)alloc((size_t)N*16);
    float*  dinv    = (float*) alloc((size_t)N*4);
    float*  bn      = (float*) alloc(64*4);
    int*    cnt     = (int*)   alloc((size_t)N*4);
    int*    rowptr  = (int*)   alloc((size_t)N*4);
    float*  part    = (float*) alloc((size_t)(N/4)*32*4);  // gat partials (N/4 rows x 32)
    float*  part2   = (float*) alloc(8192*4);
    int*    csr_src = (int*)   alloc((size_t)E*4);
    u32*    staging = (u32*)   alloc((size_t)NCB*CHUNK*4);
    int*    chunk_off = (int*) alloc((size_t)NCB*256*4);
    int*    chunk_cnt = (int*) alloc((size_t)NCB*256*4);
    int*    btot_pad  = (int*) alloc(((size_t)NBUCK*16 + 64)*4);   // + counters tail
    int*    ctr1      = btot_pad + (size_t)NBUCK*16;
    int*    ctr2      = ctr1 + 1;
    u32*    hrow    = (u32*)hreg;
    uint4*  xws     = (uint4*)hreg;                       // reuse after k_gat
    float*  gout    = (float*)(hreg + (size_t)N*16);

    hipMemsetAsync(btot_pad, 0, ((size_t)NBUCK*16 + 64)*4, stream);

    dim3 tb(TPB);
    dim3 tbb(TPB_BIN);
    int gbN = (N+TPB-1)/TPB;
    int nbGat = N/4;          // divisible by 8
    int nbGcn = N/16;         // divisible by 8

    k_bin1   <<<NCB,   tbb, 0, stream>>>(ei, staging, chunk_off, chunk_cnt, btot_pad, E);
    k_bin2   <<<NBUCK, tbb, 0, stream>>>(staging, chunk_off, chunk_cnt, btot_pad, rowptr, cnt, csr_src, NCB);
    k1_embed <<<gbN,   tb, 0, stream>>>(x, W_gat, atts, attd, hrow, a_dst4, N);
    k_gat    <<<nbGat, tb, 0, stream>>>(rowptr, cnt, csr_src, hrow, (const float*)a_dst4,
                                        b_gat, W_ht, b_ht, out_ht, part, N, nbGat/8);
    k_bnred16 <<<256,  tb, 0, stream>>>(part, part2, bn, ctr1);
    k5_bn1_gcnmm<<<gbN, tb, 0, stream>>>(out_ht, bn, g1, be1, W_gcn, cnt, dinv, xws, N);
    k_gcn    <<<nbGcn, tb, 0, stream>>>(rowptr, cnt, csr_src, dinv, xws, b_gcn, gout, part,
                                        bn+32, ctr2, N, nbGcn/8);
    k8_head  <<<B,     tb, 0, stream>>>(gout, bn+32, g2, be2, W1, b1, W2, b2, Wt, bt, Wmu, bmu, Wls, bls, out, N, B);
}

// Round 12
// 213.065 us; speedup vs baseline: 4.0925x; 4.0925x over previous
//
#include <hip/hip_runtime.h>
#include <hip/hip_bf16.h>
#include <cstddef>

#define TPB 256
#define TPB_BIN 1024
#define NPB 512        // nodes per bucket
#define BSH 9          // log2(NPB)
#define CHUNK 8192     // edges per k_bin1 block

typedef unsigned int u32;

__device__ __forceinline__ float lrelu(float v, float s){ return v > 0.f ? v : s*v; }

__device__ __forceinline__ unsigned short bf16_rne(float f){
    u32 u = __float_as_uint(f);
    u += 0x7FFFu + ((u >> 16) & 1u);
    return (unsigned short)(u >> 16);
}
__device__ __forceinline__ float bf_lo(u32 w){ return __uint_as_float(w << 16); }
__device__ __forceinline__ float bf_hi(u32 w){ return __uint_as_float(w & 0xFFFF0000u); }

// ---------------- K1: h = x @ W_gat; merged 128B node row [a_src x3 | pad | h bf16 x48 | pad] ----------------
__global__ __launch_bounds__(TPB) void k1_embed(
    const float* __restrict__ x, const float* __restrict__ Wg,
    const float* __restrict__ atts, const float* __restrict__ attd,
    u32* __restrict__ hrow, float4* __restrict__ a_dst4, int N)
{
    __shared__ float Ws[32*48];
    __shared__ float As[48], Ad[48];
    for (int i = threadIdx.x; i < 32*48; i += TPB) Ws[i] = Wg[i];
    if (threadIdx.x < 48){ As[threadIdx.x] = atts[threadIdx.x]; Ad[threadIdx.x] = attd[threadIdx.x]; }
    __syncthreads();
    int n = blockIdx.x*TPB + threadIdx.x;
    if (n >= N) return;
    float xr[32];
    const float4* xp = (const float4*)(x + (size_t)n*32);
    #pragma unroll
    for (int i=0;i<8;i++){ float4 v = xp[i]; xr[4*i+0]=v.x; xr[4*i+1]=v.y; xr[4*i+2]=v.z; xr[4*i+3]=v.w; }
    float hv[48];
    #pragma unroll 4
    for (int j=0;j<48;j++){
        float acc = 0.f;
        #pragma unroll
        for (int i=0;i<32;i++) acc = fmaf(xr[i], Ws[i*48+j], acc);
        hv[j] = acc;
    }
    float asv[3], adv[3];
    #pragma unroll
    for (int hh=0;hh<3;hh++){
        float s0=0.f, s1=0.f;
        #pragma unroll
        for (int d=0;d<16;d++){ s0 = fmaf(hv[hh*16+d], As[hh*16+d], s0); s1 = fmaf(hv[hh*16+d], Ad[hh*16+d], s1); }
        asv[hh]=s0; adv[hh]=s1;
    }
    u32 w[24];
    #pragma unroll
    for (int q=0;q<12;q++){
        w[2*q]   = (u32)bf16_rne(hv[4*q+0]) | ((u32)bf16_rne(hv[4*q+1]) << 16);
        w[2*q+1] = (u32)bf16_rne(hv[4*q+2]) | ((u32)bf16_rne(hv[4*q+3]) << 16);
    }
    uint4* hp4 = (uint4*)(hrow + (size_t)n*32);
    hp4[0] = make_uint4(__float_as_uint(asv[0]), __float_as_uint(asv[1]), __float_as_uint(asv[2]), 0u);
    #pragma unroll
    for (int i=0;i<6;i++) hp4[1+i] = make_uint4(w[4*i],w[4*i+1],w[4*i+2],w[4*i+3]);
    hp4[7] = make_uint4(0u,0u,0u,0u);
    a_dst4[n] = make_float4(adv[0],adv[1],adv[2],0.f);
}

// ---------------- k_bin1: chunk -> bucket-grouped block-private staging (1024 threads, wave-scan) ----------------
__global__ __launch_bounds__(TPB_BIN) void k_bin1(
    const int* __restrict__ ei, u32* __restrict__ staging,
    int* __restrict__ chunk_off, int* __restrict__ chunk_cnt,
    int* __restrict__ btot_pad, int E)
{
    __shared__ uint2 stash[CHUNK];
    __shared__ int lcnt[256], lcur[256];
    int t = threadIdx.x;
    int blockStart = blockIdx.x * CHUNK;
    int len = E - blockStart; if (len > CHUNK) len = CHUNK; if (len < 0) len = 0;
    if (t < 256) lcnt[t] = 0;
    __syncthreads();
    for (int i = t; i < len; i += TPB_BIN){
        int s = ei[blockStart + i];
        int d = ei[E + blockStart + i];
        stash[i] = make_uint2((unsigned)s, (unsigned)d);
        atomicAdd(&lcnt[d >> BSH], 1);
    }
    __syncthreads();
    if (t < 256){
        int myc = lcnt[t];
        atomicAdd(&btot_pad[t*16], myc);
        chunk_cnt[blockIdx.x*256 + t] = myc;
    }
    __syncthreads();
    if (t < 64){
        int v0=lcnt[4*t+0], v1=lcnt[4*t+1], v2=lcnt[4*t+2], v3=lcnt[4*t+3];
        int s = v0+v1+v2+v3, tot = s;
        #pragma unroll
        for (int off=1; off<64; off<<=1){ int xch = __shfl_up(s, off); if (t >= off) s += xch; }
        int base = s - tot;
        lcur[4*t+0]=base; lcur[4*t+1]=base+v0; lcur[4*t+2]=base+v0+v1; lcur[4*t+3]=base+v0+v1+v2;
    }
    __syncthreads();
    if (t < 256) chunk_off[blockIdx.x*256 + t] = lcur[t];
    __syncthreads();
    for (int i = t; i < len; i += TPB_BIN){
        uint2 e = stash[i];
        int b = (int)(e.y >> BSH);
        int pos = atomicAdd(&lcur[b], 1);
        staging[blockStart + pos] = e.x | ((e.y & (NPB-1u)) << 17);
    }
}

// ---------------- k_bin2: per-bucket assemble via direct chunk-segment iteration (no binary search) ----------------
__global__ __launch_bounds__(TPB_BIN) void k_bin2(
    const u32* __restrict__ staging,
    const int* __restrict__ chunk_off, const int* __restrict__ chunk_cnt,
    const int* __restrict__ btot_pad, int* __restrict__ rowptr, int* __restrict__ cnt_g,
    int* __restrict__ csr_src, int NCB)
{
    __shared__ int co[256], cl[256];
    __shared__ int lcnt[NPB], lcur[NPB];
    __shared__ int cbs;
    int b = blockIdx.x, t = threadIdx.x;
    if (t < 256){
        co[t] = (t < NCB) ? chunk_off[t*256 + b] : 0;
        cl[t] = (t < NCB) ? chunk_cnt[t*256 + b] : 0;
    }
    if (t < NPB) lcnt[t] = 0;
    if (t < 64){
        int s = 0;
        for (int i=t; i<b; i+=64) s += btot_pad[i*16];
        #pragma unroll
        for (int off=32; off; off>>=1) s += __shfl_xor(s, off);
        if (t == 0) cbs = s;
    }
    __syncthreads();
    int cb = cbs;
    int wv = t >> 6, lane = t & 63;   // 16 waves
    for (int c = wv; c < NCB; c += 16){
        int len = cl[c];
        size_t base = (size_t)c*CHUNK + co[c];
        for (int i = lane; i < len; i += 64){
            u32 val = staging[base + i];
            atomicAdd(&lcnt[(val>>17)&(NPB-1u)], 1);
        }
    }
    __syncthreads();
    if (t < 64){
        int v[8]; int ss = 0;
        #pragma unroll
        for (int k=0;k<8;k++){ v[k] = lcnt[8*t+k]; ss += v[k]; }
        int tot = ss;
        #pragma unroll
        for (int off=1; off<64; off<<=1){ int xch = __shfl_up(ss, off); if (t >= off) ss += xch; }
        int base = ss - tot;
        #pragma unroll
        for (int k=0;k<8;k++){ lcur[8*t+k] = base; base += v[k]; }
    }
    __syncthreads();
    if (t < NPB){ rowptr[b*NPB + t] = cb + lcur[t]; cnt_g[b*NPB + t] = lcnt[t]; }
    __syncthreads();
    for (int c = wv; c < NCB; c += 16){
        int len = cl[c];
        size_t base = (size_t)c*CHUNK + co[c];
        for (int i = lane; i < len; i += 64){
            u32 val = staging[base + i];
            int node = (int)((val>>17)&(NPB-1u));
            int pos = atomicAdd(&lcur[node],1);
            csr_src[cb+pos] = (int)(val & 0x1FFFFu);
        }
    }
}

// ---------------- K_gat (R9 version): wave/node; uniform-trip preloaded-index gather, LDS epilogue, fused BN1 ----------------
__global__ __launch_bounds__(TPB) void k_gat(
    const int* __restrict__ rowptr, const int* __restrict__ cnt, const int* __restrict__ csr_src,
    const u32* __restrict__ hrow, const float* __restrict__ a_dstf,
    const float* __restrict__ b_gat,
    const float* __restrict__ W_ht, const float* __restrict__ b_ht,
    float* __restrict__ out_ht, float* __restrict__ part, int N, int cpx)
{
    __shared__ float Wh[768];
    __shared__ float bg[48], bh[16];
    __shared__ float gl[4][52];
    __shared__ float ls2[4][16];
    for (int i=threadIdx.x;i<768;i+=TPB) Wh[i]=W_ht[i];
    if (threadIdx.x<48) bg[threadIdx.x]=b_gat[threadIdx.x];
    if (threadIdx.x<16) bh[threadIdx.x]=b_ht[threadIdx.x];
    __syncthreads();
    int bid = blockIdx.x;
    int bid2 = (bid & 7)*cpx + (bid >> 3);       // XCD-contiguous swizzle (gridDim % 8 == 0)
    int lane = threadIdx.x & 63;
    int wv = threadIdx.x >> 6;
    int n = bid2*4 + wv;                          // grid = N/4 exactly

    int g = lane>>4, q = lane&15;
    int hq = (q < 12) ? (q >> 2) : (q - 12);
    if (q == 15) hq = 0;
    bool is_msg = (q < 12);
    bool is_z   = (q >= 12 && q < 15);

    float adh   = a_dstf[(size_t)n*4 + hq];
    float asn_h = __uint_as_float(hrow[(size_t)n*32 + hq]);
    float wself = __expf(lrelu(asn_h + adh, 0.2f));

    int rs = rowptr[n];
    int deg = cnt[n];

    float4 acc = make_float4(0.f,0.f,0.f,0.f);
    float zacc = 0.f;

    for (int base = 0; base < deg; base += 64){
        int m = deg - base; if (m > 64) m = 64;           // wave-uniform
        int idx = csr_src[rs + base + (lane < m ? lane : 0)];
        int niter = (m + 15) >> 4;                        // wave-uniform trip count
        for (int i = 0; i < niter; i++){
            int jj = g + (i << 4);                        // lanes jj..jj+12 always in [0,63]
            int s0=__shfl(idx,jj), s1=__shfl(idx,jj+4), s2=__shfl(idx,jj+8), s3=__shfl(idx,jj+12);
            const u32* p0 = hrow + (size_t)s0*32;
            const u32* p1 = hrow + (size_t)s1*32;
            const u32* p2 = hrow + (size_t)s2*32;
            const u32* p3 = hrow + (size_t)s3*32;
            float av0=__uint_as_float(p0[hq]);
            float av1=__uint_as_float(p1[hq]);
            float av2=__uint_as_float(p2[hq]);
            float av3=__uint_as_float(p3[hq]);
            uint2 r0,r1,r2,r3;
            if (is_msg){
                r0=*(const uint2*)(p0+4+2*q); r1=*(const uint2*)(p1+4+2*q);
                r2=*(const uint2*)(p2+4+2*q); r3=*(const uint2*)(p3+4+2*q);
            }
            float w0 = (jj      < m) ? __expf(lrelu(av0+adh,0.2f)) : 0.f;
            float w1 = (jj + 4  < m) ? __expf(lrelu(av1+adh,0.2f)) : 0.f;
            float w2 = (jj + 8  < m) ? __expf(lrelu(av2+adh,0.2f)) : 0.f;
            float w3 = (jj + 12 < m) ? __expf(lrelu(av3+adh,0.2f)) : 0.f;
            if (is_msg){
                acc.x=fmaf(w0,bf_lo(r0.x),acc.x); acc.y=fmaf(w0,bf_hi(r0.x),acc.y);
                acc.z=fmaf(w0,bf_lo(r0.y),acc.z); acc.w=fmaf(w0,bf_hi(r0.y),acc.w);
                acc.x=fmaf(w1,bf_lo(r1.x),acc.x); acc.y=fmaf(w1,bf_hi(r1.x),acc.y);
                acc.z=fmaf(w1,bf_lo(r1.y),acc.z); acc.w=fmaf(w1,bf_hi(r1.y),acc.w);
                acc.x=fmaf(w2,bf_lo(r2.x),acc.x); acc.y=fmaf(w2,bf_hi(r2.x),acc.y);
                acc.z=fmaf(w2,bf_lo(r2.y),acc.z); acc.w=fmaf(w2,bf_hi(r2.y),acc.w);
                acc.x=fmaf(w3,bf_lo(r3.x),acc.x); acc.y=fmaf(w3,bf_hi(r3.x),acc.y);
                acc.z=fmaf(w3,bf_lo(r3.y),acc.z); acc.w=fmaf(w3,bf_hi(r3.y),acc.w);
            } else if (is_z){
                zacc += (w0+w1)+(w2+w3);
            }
        }
    }

    #pragma unroll
    for (int off=16; off<64; off<<=1){
        acc.x += __shfl_xor(acc.x, off); acc.y += __shfl_xor(acc.y, off);
        acc.z += __shfl_xor(acc.z, off); acc.w += __shfl_xor(acc.w, off);
        zacc  += __shfl_xor(zacc,  off);
    }
    float z_mine = __shfl(zacc, 12 + hq) + wself;

    if (g==0 && q<12){
        uint2 hs = *(const uint2*)(hrow + (size_t)n*32 + 4 + 2*q);
        float inv = 1.f / z_mine;
        float4 gq;
        gq.x = (acc.x + wself*bf_lo(hs.x))*inv + bg[4*q+0];
        gq.y = (acc.y + wself*bf_hi(hs.x))*inv + bg[4*q+1];
        gq.z = (acc.z + wself*bf_lo(hs.y))*inv + bg[4*q+2];
        gq.w = (acc.w + wself*bf_hi(hs.y))*inv + bg[4*q+3];
        *(float4*)&gl[wv][4*q] = gq;
    }
    __syncthreads();
    int j16 = lane & 15, pr = lane >> 4;
    float oacc = 0.f;
    const float* gv = &gl[wv][pr*12];
    #pragma unroll
    for (int k=0;k<12;k++) oacc = fmaf(gv[k], Wh[(pr*12+k)*16 + j16], oacc);
    oacc += __shfl_xor(oacc, 16);
    oacc += __shfl_xor(oacc, 32);
    float oval = oacc + bh[j16];
    if (lane < 16){
        out_ht[(size_t)n*16 + lane] = oval;
        ls2[wv][lane] = oval;
    }
    __syncthreads();
    int t = threadIdx.x;
    if (t < 16){
        float s=0.f, qd=0.f;
        #pragma unroll
        for (int w2=0;w2<4;w2++){ float v=ls2[w2][t]; s+=v; qd+=v*v; }
        part[(size_t)bid*32 + t] = s;
        part[(size_t)bid*32 + 16 + t] = qd;
    }
}

// mid-reduce 32768 rows x 32 -> 256 rows x 32 (256 blocks, 128 rows each)
__global__ __launch_bounds__(TPB) void k_bnmid16(const float* __restrict__ part, float* __restrict__ part2)
{
    __shared__ float ls[8][32];
    int t = threadIdx.x, b = blockIdx.x;
    int col = t & 31, grp = t >> 5;
    float s = 0.f;
    #pragma unroll
    for (int i=0;i<16;i++){ int r = b*128 + grp*16 + i; s += part[(size_t)r*32 + col]; }
    ls[grp][col] = s; __syncthreads();
    if (t < 32){
        float a = 0.f;
        #pragma unroll
        for (int g=0; g<8; g++) a += ls[g][t];
        part2[(size_t)b*32 + t] = a;
    }
}

__global__ __launch_bounds__(TPB) void k_bnfin16(const float* __restrict__ part2, float* __restrict__ bn, int NB)
{
    __shared__ float ls[8][32];
    int t = threadIdx.x, col = t & 31, grp = t >> 5;
    float s = 0.f;
    for (int r=grp; r<NB; r+=8) s += part2[(size_t)r*32+col];
    ls[grp][col] = s; __syncthreads();
    if (t < 32){
        float a = 0.f;
        #pragma unroll
        for (int g=0; g<8; g++) a += ls[g][t];
        bn[t] = a;
    }
}

// mid-reduce 8192 rows x 16 -> 64 rows x 16 (64 blocks)
__global__ __launch_bounds__(TPB) void k_bnmid8(const float* __restrict__ part, float* __restrict__ part2)
{
    __shared__ float ls[16][16];
    int t = threadIdx.x, b = blockIdx.x;
    int col = t & 15, grp = t >> 4;
    float s = 0.f;
    #pragma unroll
    for (int i=0;i<8;i++){ int r = b*128 + grp + 16*i; s += part[(size_t)r*16 + col]; }
    ls[grp][col] = s; __syncthreads();
    if (t < 16){
        float a = 0.f;
        #pragma unroll
        for (int g=0; g<16; g++) a += ls[g][t];
        part2[(size_t)b*16 + t] = a;
    }
}

__global__ __launch_bounds__(TPB) void k_bnfin8(const float* __restrict__ part2, float* __restrict__ bn, int NB)
{
    __shared__ float ls[16][16];
    int t = threadIdx.x, col = t & 15, grp = t >> 4;
    float s = 0.f;
    for (int r=grp; r<NB; r+=16) s += part2[(size_t)r*16+col];
    ls[grp][col] = s; __syncthreads();
    if (t < 16){
        float a = 0.f;
        #pragma unroll
        for (int g=0; g<16; g++) a += ls[g][t];
        bn[t] = a;
    }
}

// ---------------- K5: BN1 apply + GCN matmul + write dinv-prescaled bf16 xws ----------------
__global__ __launch_bounds__(TPB) void k5_bn1_gcnmm(
    const float* __restrict__ out_ht, const float* __restrict__ bn,
    const float* __restrict__ g1, const float* __restrict__ be1,
    const float* __restrict__ W_gcn, const int* __restrict__ cnt,
    float* __restrict__ dinv, uint4* __restrict__ xws, int N)
{
    __shared__ float sc[16], sh[16], Wg[128];
    int t = threadIdx.x;
    if (t < 16){
        float mu  = bn[t]/(float)N;
        float var = bn[16+t]/(float)N - mu*mu;
        float s = rsqrtf(var+1e-5f)*g1[t];
        sc[t]=s; sh[t]=be1[t]-mu*s;
    }
    if (t < 128) Wg[t] = W_gcn[t];
    __syncthreads();
    int n = blockIdx.x*TPB + t;
    if (n >= N) return;
    float v[16];
    const float4* ip = (const float4*)(out_ht + (size_t)n*16);
    #pragma unroll
    for (int q=0;q<4;q++){
        float4 vv = ip[q];
        v[4*q+0]=vv.x*sc[4*q+0]+sh[4*q+0];
        v[4*q+1]=vv.y*sc[4*q+1]+sh[4*q+1];
        v[4*q+2]=vv.z*sc[4*q+2]+sh[4*q+2];
        v[4*q+3]=vv.w*sc[4*q+3]+sh[4*q+3];
    }
    float dv = rsqrtf((float)(cnt[n]+1));
    float o[8];
    #pragma unroll
    for (int k=0;k<8;k++){
        float acc=0.f;
        #pragma unroll
        for (int j=0;j<16;j++) acc = fmaf(v[j], Wg[j*8+k], acc);
        o[k]=acc*dv;
    }
    u32 w0 = (u32)bf16_rne(o[0]) | ((u32)bf16_rne(o[1])<<16);
    u32 w1 = (u32)bf16_rne(o[2]) | ((u32)bf16_rne(o[3])<<16);
    u32 w2 = (u32)bf16_rne(o[4]) | ((u32)bf16_rne(o[5])<<16);
    u32 w3 = (u32)bf16_rne(o[6]) | ((u32)bf16_rne(o[7])<<16);
    xws[n] = make_uint4(w0,w1,w2,w3);
    dinv[n] = dv;
}

// ---------------- K_gcn (R10 version): gather + fused BN2 partials, NO fence/counter ----------------
__global__ __launch_bounds__(TPB) void k_gcn(
    const int* __restrict__ rowptr, const int* __restrict__ cnt, const int* __restrict__ csr_src,
    const float* __restrict__ dinv, const uint4* __restrict__ xws,
    const float* __restrict__ b_gcn, float* __restrict__ gout, float* __restrict__ part, int N, int cpx)
{
    __shared__ float ls[16][16];
    int bid = blockIdx.x;
    int bid2 = (bid & 7)*cpx + (bid >> 3);
    int t = threadIdx.x;
    int node = bid2*16 + (t >> 4);
    int sub  = t & 15;
    int grp  = t >> 4;
    float val[8];
    #pragma unroll
    for (int k=0;k<8;k++) val[k]=0.f;
    if (node < N){
        int rs = rowptr[node], re = rs + cnt[node];
        float a0=0.f,a1=0.f,a2=0.f,a3=0.f,a4=0.f,a5=0.f,a6=0.f,a7=0.f;
        for (int j=rs+sub; j<re; j+=16){
            int s = csr_src[j];
            uint4 r = xws[s];
            a0 += bf_lo(r.x); a1 += bf_hi(r.x);
            a2 += bf_lo(r.y); a3 += bf_hi(r.y);
            a4 += bf_lo(r.z); a5 += bf_hi(r.z);
            a6 += bf_lo(r.w); a7 += bf_hi(r.w);
        }
        #pragma unroll
        for (int off=1; off<16; off<<=1){
            a0 += __shfl_xor(a0, off); a1 += __shfl_xor(a1, off);
            a2 += __shfl_xor(a2, off); a3 += __shfl_xor(a3, off);
            a4 += __shfl_xor(a4, off); a5 += __shfl_xor(a5, off);
            a6 += __shfl_xor(a6, off); a7 += __shfl_xor(a7, off);
        }
        if (sub == 0){
            uint4 r = xws[node];
            a0 += bf_lo(r.x); a1 += bf_hi(r.x);
            a2 += bf_lo(r.y); a3 += bf_hi(r.y);
            a4 += bf_lo(r.z); a5 += bf_hi(r.z);
            a6 += bf_lo(r.w); a7 += bf_hi(r.w);
            float dd = dinv[node];
            val[0]=fmaf(dd,a0,b_gcn[0]); val[1]=fmaf(dd,a1,b_gcn[1]);
            val[2]=fmaf(dd,a2,b_gcn[2]); val[3]=fmaf(dd,a3,b_gcn[3]);
            val[4]=fmaf(dd,a4,b_gcn[4]); val[5]=fmaf(dd,a5,b_gcn[5]);
            val[6]=fmaf(dd,a6,b_gcn[6]); val[7]=fmaf(dd,a7,b_gcn[7]);
            float4* op = (float4*)(gout + (size_t)node*8);
            op[0] = make_float4(val[0],val[1],val[2],val[3]);
            op[1] = make_float4(val[4],val[5],val[6],val[7]);
        }
    }
    if (sub == 0){
        #pragma unroll
        for (int k=0;k<8;k++){ ls[grp][k] = val[k]; ls[grp][8+k] = val[k]*val[k]; }
    }
    __syncthreads();
    if (t < 16){
        float s = 0.f;
        #pragma unroll
        for (int g2=0; g2<16; g2++) s += ls[g2][t];
        part[(size_t)bid*16 + t] = s;
    }
}

// ---------------- K8: BN2 apply + per-graph dense head ----------------
__global__ __launch_bounds__(TPB) void k8_head(
    const float* __restrict__ gcn, const float* __restrict__ bn2,
    const float* __restrict__ g2, const float* __restrict__ be2,
    const float* __restrict__ W1, const float* __restrict__ b1,
    const float* __restrict__ W2, const float* __restrict__ b2,
    const float* __restrict__ Wt, const float* __restrict__ bt,
    const float* __restrict__ Wmu, const float* __restrict__ bmu,
    const float* __restrict__ Wls, const float* __restrict__ bls,
    float* __restrict__ out, int N, int B)
{
    __shared__ float v[4096];
    __shared__ float red[8][32];
    __shared__ float y1[32], y2[16], y3[64];
    int b = blockIdx.x, t = threadIdx.x;
    float sc[8], sh[8];
    #pragma unroll
    for (int k=0;k<8;k++){
        float mu  = bn2[k]/(float)N;
        float var = bn2[8+k]/(float)N - mu*mu;
        float s = rsqrtf(var+1e-5f)*g2[k];
        sc[k]=s; sh[k]=be2[k]-mu*s;
    }
    const float* src = gcn + (size_t)b*4096;
    for (int i=t;i<4096;i+=TPB){ int k=i&7; v[i]=src[i]*sc[k]+sh[k]; }
    __syncthreads();
    int j = t & 31, c = t >> 5;
    float p = 0.f;
    int base = c*512;
    for (int i=0;i<512;i++) p = fmaf(v[base+i], W1[(size_t)(base+i)*32+j], p);
    red[c][j] = p;
    __syncthreads();
    if (t < 32){
        float a = b1[t];
        #pragma unroll
        for (int cc=0;cc<8;cc++) a += red[cc][t];
        y1[t] = lrelu(a, 0.01f);
    }
    __syncthreads();
    if (t < 16){
        float a = b2[t];
        #pragma unroll
        for (int i=0;i<32;i++) a = fmaf(y1[i], W2[i*16+t], a);
        y2[t] = lrelu(a, 0.01f);
    }
    __syncthreads();
    if (t < 64){
        float a = bt[t];
        #pragma unroll
        for (int i=0;i<16;i++) a = fmaf(y2[i], Wt[i*64+t], a);
        y3[t] = lrelu(a, 0.01f);
    }
    __syncthreads();
    if (t < 64){
        float amu = bmu[t], als = bls[t];
        #pragma unroll
        for (int i=0;i<64;i++){ amu = fmaf(y3[i], Wmu[i*64+t], amu); als = fmaf(y3[i], Wls[i*64+t], als); }
        out[(size_t)b*64 + t] = amu;
        out[(size_t)B*64 + (size_t)b*64 + t] = als;
    }
}

extern "C" void kernel_launch(void* const* d_in, const int* in_sizes, int n_in,
                              void* d_out, int out_size, void* d_ws, size_t ws_size,
                              hipStream_t stream)
{
    const float* x     = (const float*)d_in[0];
    const int*   ei    = (const int*)  d_in[1];
    const float* W_gat = (const float*)d_in[2];
    const float* atts  = (const float*)d_in[3];
    const float* attd  = (const float*)d_in[4];
    const float* b_gat = (const float*)d_in[5];
    const float* W_ht  = (const float*)d_in[6];
    const float* b_ht  = (const float*)d_in[7];
    const float* g1    = (const float*)d_in[8];
    const float* be1   = (const float*)d_in[9];
    const float* W_gcn = (const float*)d_in[10];
    const float* b_gcn = (const float*)d_in[11];
    const float* g2    = (const float*)d_in[12];
    const float* be2   = (const float*)d_in[13];
    const float* W1    = (const float*)d_in[14];
    const float* b1    = (const float*)d_in[15];
    const float* W2    = (const float*)d_in[16];
    const float* b2    = (const float*)d_in[17];
    const float* Wt    = (const float*)d_in[18];
    const float* bt    = (const float*)d_in[19];
    const float* Wmu   = (const float*)d_in[20];
    const float* bmu   = (const float*)d_in[21];
    const float* Wls   = (const float*)d_in[22];
    const float* bls   = (const float*)d_in[23];
    float* out = (float*)d_out;

    const int N = in_sizes[0] / 32;
    const int E = in_sizes[1] / 2;
    const int B = N / 512;
    const int NBUCK = N / NPB;
    const int NCB = (E + CHUNK - 1) / CHUNK;

    char* wsb = (char*)d_ws;
    size_t off = 0;
    auto alloc = [&](size_t bytes){ void* p = wsb + off; off += (bytes + 255) & ~(size_t)255; return p; };
    char*   hreg    = (char*)  alloc((size_t)N*128);     // merged node rows; later xws+gout
    float*  out_ht  = (float*) alloc((size_t)N*16*4);
    float4* a_dst4  = (float4*)alloc((size_t)N*16);
    float*  dinv    = (float*) alloc((size_t)N*4);
    float*  bn      = (float*) alloc(64*4);
    int*    cnt     = (int*)   alloc((size_t)N*4);
    int*    rowptr  = (int*)   alloc((size_t)N*4);
    float*  part    = (float*) alloc((size_t)(N/4)*32*4);  // gat partials (N/4 rows x 32)
    float*  part2   = (float*) alloc(8192*4);
    int*    csr_src = (int*)   alloc((size_t)E*4);
    u32*    staging = (u32*)   alloc((size_t)NCB*CHUNK*4);
    int*    chunk_off = (int*) alloc((size_t)NCB*256*4);
    int*    chunk_cnt = (int*) alloc((size_t)NCB*256*4);
    int*    btot_pad  = (int*) alloc((size_t)NBUCK*16*4);
    u32*    hrow    = (u32*)hreg;
    uint4*  xws     = (uint4*)hreg;                       // reuse after k_gat
    float*  gout    = (float*)(hreg + (size_t)N*16);

    hipMemsetAsync(btot_pad, 0, (size_t)NBUCK*16*4, stream);

    dim3 tb(TPB);
    dim3 tbb(TPB_BIN);
    int gbN = (N+TPB-1)/TPB;
    int nbGat = N/4;          // divisible by 8
    int nbGcn = N/16;         // divisible by 8

    k_bin1   <<<NCB,   tbb, 0, stream>>>(ei, staging, chunk_off, chunk_cnt, btot_pad, E);
    k_bin2   <<<NBUCK, tbb, 0, stream>>>(staging, chunk_off, chunk_cnt, btot_pad, rowptr, cnt, csr_src, NCB);
    k1_embed <<<gbN,   tb, 0, stream>>>(x, W_gat, atts, attd, hrow, a_dst4, N);
    k_gat    <<<nbGat, tb, 0, stream>>>(rowptr, cnt, csr_src, hrow, (const float*)a_dst4,
                                        b_gat, W_ht, b_ht, out_ht, part, N, nbGat/8);
    k_bnmid16 <<<256,  tb, 0, stream>>>(part, part2);
    k_bnfin16 <<<1,    tb, 0, stream>>>(part2, bn, 256);
    k5_bn1_gcnmm<<<gbN, tb, 0, stream>>>(out_ht, bn, g1, be1, W_gcn, cnt, dinv, xws, N);
    k_gcn    <<<nbGcn, tb, 0, stream>>>(rowptr, cnt, csr_src, dinv, xws, b_gcn, gout, part, N, nbGcn/8);
    k_bnmid8 <<<64,    tb, 0, stream>>>(part, part2);
    k_bnfin8 <<<1,     tb, 0, stream>>>(part2, bn+32, 64);
    k8_head  <<<B,     tb, 0, stream>>>(gout, bn+32, g2, be2, W1, b1, W2, b2, Wt, bt, Wmu, bmu, Wls, bls, out, N, B);
}

// Round 13
// 210.695 us; speedup vs baseline: 4.1385x; 1.0112x over previous
//
#include <hip/hip_runtime.h>
#include <hip/hip_bf16.h>
#include <cstddef>

#define TPB 256
#define TPB_BIN 1024
#define NPB 512        // nodes per bucket
#define BSH 9          // log2(NPB)
#define CHUNK 8192     // edges per k_bin1 block

typedef unsigned int u32;

__device__ __forceinline__ float lrelu(float v, float s){ return v > 0.f ? v : s*v; }

__device__ __forceinline__ unsigned short bf16_rne(float f){
    u32 u = __float_as_uint(f);
    u += 0x7FFFu + ((u >> 16) & 1u);
    return (unsigned short)(u >> 16);
}
__device__ __forceinline__ float bf_lo(u32 w){ return __uint_as_float(w << 16); }
__device__ __forceinline__ float bf_hi(u32 w){ return __uint_as_float(w & 0xFFFF0000u); }

// ---------------- K1: h = x @ W_gat; merged 128B node row [a_src x3 | pad | h bf16 x48 | a_dst x3 | pad] ----------------
__global__ __launch_bounds__(TPB) void k1_embed(
    const float* __restrict__ x, const float* __restrict__ Wg,
    const float* __restrict__ atts, const float* __restrict__ attd,
    u32* __restrict__ hrow, int N)
{
    __shared__ float Ws[32*48];
    __shared__ float As[48], Ad[48];
    for (int i = threadIdx.x; i < 32*48; i += TPB) Ws[i] = Wg[i];
    if (threadIdx.x < 48){ As[threadIdx.x] = atts[threadIdx.x]; Ad[threadIdx.x] = attd[threadIdx.x]; }
    __syncthreads();
    int n = blockIdx.x*TPB + threadIdx.x;
    if (n >= N) return;
    float xr[32];
    const float4* xp = (const float4*)(x + (size_t)n*32);
    #pragma unroll
    for (int i=0;i<8;i++){ float4 v = xp[i]; xr[4*i+0]=v.x; xr[4*i+1]=v.y; xr[4*i+2]=v.z; xr[4*i+3]=v.w; }
    float hv[48];
    #pragma unroll 4
    for (int j=0;j<48;j++){
        float acc = 0.f;
        #pragma unroll
        for (int i=0;i<32;i++) acc = fmaf(xr[i], Ws[i*48+j], acc);
        hv[j] = acc;
    }
    float asv[3], adv[3];
    #pragma unroll
    for (int hh=0;hh<3;hh++){
        float s0=0.f, s1=0.f;
        #pragma unroll
        for (int d=0;d<16;d++){ s0 = fmaf(hv[hh*16+d], As[hh*16+d], s0); s1 = fmaf(hv[hh*16+d], Ad[hh*16+d], s1); }
        asv[hh]=s0; adv[hh]=s1;
    }
    u32 w[24];
    #pragma unroll
    for (int q=0;q<12;q++){
        w[2*q]   = (u32)bf16_rne(hv[4*q+0]) | ((u32)bf16_rne(hv[4*q+1]) << 16);
        w[2*q+1] = (u32)bf16_rne(hv[4*q+2]) | ((u32)bf16_rne(hv[4*q+3]) << 16);
    }
    uint4* hp4 = (uint4*)(hrow + (size_t)n*32);
    hp4[0] = make_uint4(__float_as_uint(asv[0]), __float_as_uint(asv[1]), __float_as_uint(asv[2]), 0u);
    #pragma unroll
    for (int i=0;i<6;i++) hp4[1+i] = make_uint4(w[4*i],w[4*i+1],w[4*i+2],w[4*i+3]);
    hp4[7] = make_uint4(__float_as_uint(adv[0]), __float_as_uint(adv[1]), __float_as_uint(adv[2]), 0u);
}

// ---------------- k_bin1: chunk -> bucket-grouped block-private staging (1024 threads, wave-scan) ----------------
__global__ __launch_bounds__(TPB_BIN) void k_bin1(
    const int* __restrict__ ei, u32* __restrict__ staging,
    int* __restrict__ chunk_off, int* __restrict__ chunk_cnt,
    int* __restrict__ btot_pad, int E)
{
    __shared__ uint2 stash[CHUNK];
    __shared__ int lcnt[256], lcur[256];
    int t = threadIdx.x;
    int blockStart = blockIdx.x * CHUNK;
    int len = E - blockStart; if (len > CHUNK) len = CHUNK; if (len < 0) len = 0;
    if (t < 256) lcnt[t] = 0;
    __syncthreads();
    for (int i = t; i < len; i += TPB_BIN){
        int s = ei[blockStart + i];
        int d = ei[E + blockStart + i];
        stash[i] = make_uint2((unsigned)s, (unsigned)d);
        atomicAdd(&lcnt[d >> BSH], 1);
    }
    __syncthreads();
    if (t < 256){
        int myc = lcnt[t];
        atomicAdd(&btot_pad[t*16], myc);
        chunk_cnt[blockIdx.x*256 + t] = myc;
    }
    __syncthreads();
    if (t < 64){
        int v0=lcnt[4*t+0], v1=lcnt[4*t+1], v2=lcnt[4*t+2], v3=lcnt[4*t+3];
        int s = v0+v1+v2+v3, tot = s;
        #pragma unroll
        for (int off=1; off<64; off<<=1){ int xch = __shfl_up(s, off); if (t >= off) s += xch; }
        int base = s - tot;
        lcur[4*t+0]=base; lcur[4*t+1]=base+v0; lcur[4*t+2]=base+v0+v1; lcur[4*t+3]=base+v0+v1+v2;
    }
    __syncthreads();
    if (t < 256) chunk_off[blockIdx.x*256 + t] = lcur[t];
    __syncthreads();
    for (int i = t; i < len; i += TPB_BIN){
        uint2 e = stash[i];
        int b = (int)(e.y >> BSH);
        int pos = atomicAdd(&lcur[b], 1);
        staging[blockStart + pos] = e.x | ((e.y & (NPB-1u)) << 17);
    }
}

// ---------------- k_bin2: per-bucket assemble via direct chunk-segment iteration ----------------
__global__ __launch_bounds__(TPB_BIN) void k_bin2(
    const u32* __restrict__ staging,
    const int* __restrict__ chunk_off, const int* __restrict__ chunk_cnt,
    const int* __restrict__ btot_pad, int* __restrict__ rowptr, int* __restrict__ cnt_g,
    int* __restrict__ csr_src, int NCB)
{
    __shared__ int co[256], cl[256];
    __shared__ int lcnt[NPB], lcur[NPB];
    __shared__ int cbs;
    int b = blockIdx.x, t = threadIdx.x;
    if (t < 256){
        co[t] = (t < NCB) ? chunk_off[t*256 + b] : 0;
        cl[t] = (t < NCB) ? chunk_cnt[t*256 + b] : 0;
    }
    if (t < NPB) lcnt[t] = 0;
    if (t < 64){
        int s = 0;
        for (int i=t; i<b; i+=64) s += btot_pad[i*16];
        #pragma unroll
        for (int off=32; off; off>>=1) s += __shfl_xor(s, off);
        if (t == 0) cbs = s;
    }
    __syncthreads();
    int cb = cbs;
    int wv = t >> 6, lane = t & 63;   // 16 waves
    for (int c = wv; c < NCB; c += 16){
        int len = cl[c];
        size_t base = (size_t)c*CHUNK + co[c];
        for (int i = lane; i < len; i += 64){
            u32 val = staging[base + i];
            atomicAdd(&lcnt[(val>>17)&(NPB-1u)], 1);
        }
    }
    __syncthreads();
    if (t < 64){
        int v[8]; int ss = 0;
        #pragma unroll
        for (int k=0;k<8;k++){ v[k] = lcnt[8*t+k]; ss += v[k]; }
        int tot = ss;
        #pragma unroll
        for (int off=1; off<64; off<<=1){ int xch = __shfl_up(ss, off); if (t >= off) ss += xch; }
        int base = ss - tot;
        #pragma unroll
        for (int k=0;k<8;k++){ lcur[8*t+k] = base; base += v[k]; }
    }
    __syncthreads();
    if (t < NPB){ rowptr[b*NPB + t] = cb + lcur[t]; cnt_g[b*NPB + t] = lcnt[t]; }
    __syncthreads();
    for (int c = wv; c < NCB; c += 16){
        int len = cl[c];
        size_t base = (size_t)c*CHUNK + co[c];
        for (int i = lane; i < len; i += 64){
            u32 val = staging[base + i];
            int node = (int)((val>>17)&(NPB-1u));
            int pos = atomicAdd(&lcur[node],1);
            csr_src[cb+pos] = (int)(val & 0x1FFFFu);
        }
    }
}

// ---------------- K_gat: wave/node; mask-free full iterations + masked tail; LDS epilogue; fused BN1 ----------------
__global__ __launch_bounds__(TPB) void k_gat(
    const int* __restrict__ rowptr, const int* __restrict__ cnt, const int* __restrict__ csr_src,
    const u32* __restrict__ hrow,
    const float* __restrict__ b_gat,
    const float* __restrict__ W_ht, const float* __restrict__ b_ht,
    float* __restrict__ out_ht, float* __restrict__ part, int N, int cpx)
{
    __shared__ float Wh[768];
    __shared__ float bg[48], bh[16];
    __shared__ float gl[4][52];
    __shared__ float ls2[4][16];
    for (int i=threadIdx.x;i<768;i+=TPB) Wh[i]=W_ht[i];
    if (threadIdx.x<48) bg[threadIdx.x]=b_gat[threadIdx.x];
    if (threadIdx.x<16) bh[threadIdx.x]=b_ht[threadIdx.x];
    __syncthreads();
    int bid = blockIdx.x;
    int bid2 = (bid & 7)*cpx + (bid >> 3);       // XCD-contiguous swizzle (gridDim % 8 == 0)
    int lane = threadIdx.x & 63;
    int wv = threadIdx.x >> 6;
    int n = bid2*4 + wv;                          // grid = N/4 exactly

    int g = lane>>4, q = lane&15;
    int hq = (q < 12) ? (q >> 2) : (q - 12);
    if (q == 15) hq = 0;
    bool is_msg = (q < 12);
    bool is_z   = (q >= 12 && q < 15);

    float adh   = __uint_as_float(hrow[(size_t)n*32 + 28 + hq]);
    float asn_h = __uint_as_float(hrow[(size_t)n*32 + hq]);
    float wself = __expf(lrelu(asn_h + adh, 0.2f));

    int rs = rowptr[n];
    int deg = cnt[n];

    float4 acc = make_float4(0.f,0.f,0.f,0.f);
    float zacc = 0.f;

    for (int base = 0; base < deg; base += 64){
        int m = deg - base; if (m > 64) m = 64;           // wave-uniform
        int idx = csr_src[rs + base + (lane < m ? lane : 0)];
        int nfull = m >> 4;                               // mask-free iterations
        for (int i = 0; i < nfull; i++){
            int jj = g + (i << 4);
            int s0=__shfl(idx,jj), s1=__shfl(idx,jj+4), s2=__shfl(idx,jj+8), s3=__shfl(idx,jj+12);
            const u32* p0 = hrow + (size_t)s0*32;
            const u32* p1 = hrow + (size_t)s1*32;
            const u32* p2 = hrow + (size_t)s2*32;
            const u32* p3 = hrow + (size_t)s3*32;
            float av0=__uint_as_float(p0[hq]);
            float av1=__uint_as_float(p1[hq]);
            float av2=__uint_as_float(p2[hq]);
            float av3=__uint_as_float(p3[hq]);
            uint2 r0,r1,r2,r3;
            if (is_msg){
                r0=*(const uint2*)(p0+4+2*q); r1=*(const uint2*)(p1+4+2*q);
                r2=*(const uint2*)(p2+4+2*q); r3=*(const uint2*)(p3+4+2*q);
            }
            float w0 = __expf(lrelu(av0+adh,0.2f));
            float w1 = __expf(lrelu(av1+adh,0.2f));
            float w2 = __expf(lrelu(av2+adh,0.2f));
            float w3 = __expf(lrelu(av3+adh,0.2f));
            if (is_msg){
                acc.x=fmaf(w0,bf_lo(r0.x),acc.x); acc.y=fmaf(w0,bf_hi(r0.x),acc.y);
                acc.z=fmaf(w0,bf_lo(r0.y),acc.z); acc.w=fmaf(w0,bf_hi(r0.y),acc.w);
                acc.x=fmaf(w1,bf_lo(r1.x),acc.x); acc.y=fmaf(w1,bf_hi(r1.x),acc.y);
                acc.z=fmaf(w1,bf_lo(r1.y),acc.z); acc.w=fmaf(w1,bf_hi(r1.y),acc.w);
                acc.x=fmaf(w2,bf_lo(r2.x),acc.x); acc.y=fmaf(w2,bf_hi(r2.x),acc.y);
                acc.z=fmaf(w2,bf_lo(r2.y),acc.z); acc.w=fmaf(w2,bf_hi(r2.y),acc.w);
                acc.x=fmaf(w3,bf_lo(r3.x),acc.x); acc.y=fmaf(w3,bf_hi(r3.x),acc.y);
                acc.z=fmaf(w3,bf_lo(r3.y),acc.z); acc.w=fmaf(w3,bf_hi(r3.y),acc.w);
            } else if (is_z){
                zacc += (w0+w1)+(w2+w3);
            }
        }
        if (m & 15){                                       // masked tail iteration
            int jj = g + (nfull << 4);                     // <= 63 always
            int s0=__shfl(idx,jj), s1=__shfl(idx,jj+4), s2=__shfl(idx,jj+8), s3=__shfl(idx,jj+12);
            const u32* p0 = hrow + (size_t)s0*32;
            const u32* p1 = hrow + (size_t)s1*32;
            const u32* p2 = hrow + (size_t)s2*32;
            const u32* p3 = hrow + (size_t)s3*32;
            float av0=__uint_as_float(p0[hq]);
            float av1=__uint_as_float(p1[hq]);
            float av2=__uint_as_float(p2[hq]);
            float av3=__uint_as_float(p3[hq]);
            uint2 r0,r1,r2,r3;
            if (is_msg){
                r0=*(const uint2*)(p0+4+2*q); r1=*(const uint2*)(p1+4+2*q);
                r2=*(const uint2*)(p2+4+2*q); r3=*(const uint2*)(p3+4+2*q);
            }
            float w0 = (jj      < m) ? __expf(lrelu(av0+adh,0.2f)) : 0.f;
            float w1 = (jj + 4  < m) ? __expf(lrelu(av1+adh,0.2f)) : 0.f;
            float w2 = (jj + 8  < m) ? __expf(lrelu(av2+adh,0.2f)) : 0.f;
            float w3 = (jj + 12 < m) ? __expf(lrelu(av3+adh,0.2f)) : 0.f;
            if (is_msg){
                acc.x=fmaf(w0,bf_lo(r0.x),acc.x); acc.y=fmaf(w0,bf_hi(r0.x),acc.y);
                acc.z=fmaf(w0,bf_lo(r0.y),acc.z); acc.w=fmaf(w0,bf_hi(r0.y),acc.w);
                acc.x=fmaf(w1,bf_lo(r1.x),acc.x); acc.y=fmaf(w1,bf_hi(r1.x),acc.y);
                acc.z=fmaf(w1,bf_lo(r1.y),acc.z); acc.w=fmaf(w1,bf_hi(r1.y),acc.w);
                acc.x=fmaf(w2,bf_lo(r2.x),acc.x); acc.y=fmaf(w2,bf_hi(r2.x),acc.y);
                acc.z=fmaf(w2,bf_lo(r2.y),acc.z); acc.w=fmaf(w2,bf_hi(r2.y),acc.w);
                acc.x=fmaf(w3,bf_lo(r3.x),acc.x); acc.y=fmaf(w3,bf_hi(r3.x),acc.y);
                acc.z=fmaf(w3,bf_lo(r3.y),acc.z); acc.w=fmaf(w3,bf_hi(r3.y),acc.w);
            } else if (is_z){
                zacc += (w0+w1)+(w2+w3);
            }
        }
    }

    #pragma unroll
    for (int off=16; off<64; off<<=1){
        acc.x += __shfl_xor(acc.x, off); acc.y += __shfl_xor(acc.y, off);
        acc.z += __shfl_xor(acc.z, off); acc.w += __shfl_xor(acc.w, off);
        zacc  += __shfl_xor(zacc,  off);
    }
    float z_mine = __shfl(zacc, 12 + hq) + wself;

    if (g==0 && q<12){
        uint2 hs = *(const uint2*)(hrow + (size_t)n*32 + 4 + 2*q);
        float inv = 1.f / z_mine;
        float4 gq;
        gq.x = (acc.x + wself*bf_lo(hs.x))*inv + bg[4*q+0];
        gq.y = (acc.y + wself*bf_hi(hs.x))*inv + bg[4*q+1];
        gq.z = (acc.z + wself*bf_lo(hs.y))*inv + bg[4*q+2];
        gq.w = (acc.w + wself*bf_hi(hs.y))*inv + bg[4*q+3];
        *(float4*)&gl[wv][4*q] = gq;
    }
    __syncthreads();
    int j16 = lane & 15, pr = lane >> 4;
    float oacc = 0.f;
    const float* gv = &gl[wv][pr*12];
    #pragma unroll
    for (int k=0;k<12;k++) oacc = fmaf(gv[k], Wh[(pr*12+k)*16 + j16], oacc);
    oacc += __shfl_xor(oacc, 16);
    oacc += __shfl_xor(oacc, 32);
    float oval = oacc + bh[j16];
    if (lane < 16){
        out_ht[(size_t)n*16 + lane] = oval;
        ls2[wv][lane] = oval;
    }
    __syncthreads();
    int t = threadIdx.x;
    if (t < 16){
        float s=0.f, qd=0.f;
        #pragma unroll
        for (int w2=0;w2<4;w2++){ float v=ls2[w2][t]; s+=v; qd+=v*v; }
        part[(size_t)bid*32 + t] = s;
        part[(size_t)bid*32 + 16 + t] = qd;
    }
}

// mid-reduce 32768 rows x 32 -> 256 rows x 32 (256 blocks, 128 rows each)
__global__ __launch_bounds__(TPB) void k_bnmid16(const float* __restrict__ part, float* __restrict__ part2)
{
    __shared__ float ls[8][32];
    int t = threadIdx.x, b = blockIdx.x;
    int col = t & 31, grp = t >> 5;
    float s = 0.f;
    #pragma unroll
    for (int i=0;i<16;i++){ int r = b*128 + grp*16 + i; s += part[(size_t)r*32 + col]; }
    ls[grp][col] = s; __syncthreads();
    if (t < 32){
        float a = 0.f;
        #pragma unroll
        for (int g=0; g<8; g++) a += ls[g][t];
        part2[(size_t)b*32 + t] = a;
    }
}

// mid-reduce 8192 rows x 16 -> 64 rows x 16 (64 blocks)
__global__ __launch_bounds__(TPB) void k_bnmid8(const float* __restrict__ part, float* __restrict__ part2)
{
    __shared__ float ls[16][16];
    int t = threadIdx.x, b = blockIdx.x;
    int col = t & 15, grp = t >> 4;
    float s = 0.f;
    #pragma unroll
    for (int i=0;i<8;i++){ int r = b*128 + grp + 16*i; s += part[(size_t)r*16 + col]; }
    ls[grp][col] = s; __syncthreads();
    if (t < 16){
        float a = 0.f;
        #pragma unroll
        for (int g=0; g<16; g++) a += ls[g][t];
        part2[(size_t)b*16 + t] = a;
    }
}

// ---------------- K5: inline BN1 finish (256x32 reduce) + BN1 apply + GCN matmul + bf16 xws ----------------
__global__ __launch_bounds__(TPB) void k5_bn1_gcnmm(
    const float* __restrict__ out_ht, const float* __restrict__ part2,
    const float* __restrict__ g1, const float* __restrict__ be1,
    const float* __restrict__ W_gcn, const int* __restrict__ cnt,
    float* __restrict__ dinv, uint4* __restrict__ xws, int N)
{
    __shared__ float ls[8][32];
    __shared__ float bnv[32];
    __shared__ float sc[16], sh[16], Wg[128];
    int t = threadIdx.x;
    {
        int col = t & 31, grp = t >> 5;
        float s = 0.f;
        #pragma unroll
        for (int i=0;i<32;i++) s += part2[(size_t)(grp + 8*i)*32 + col];
        ls[grp][col] = s;
    }
    if (t < 128) Wg[t] = W_gcn[t];
    __syncthreads();
    if (t < 32){
        float a = 0.f;
        #pragma unroll
        for (int g=0; g<8; g++) a += ls[g][t];
        bnv[t] = a;
    }
    __syncthreads();
    if (t < 16){
        float mu  = bnv[t]/(float)N;
        float var = bnv[16+t]/(float)N - mu*mu;
        float s = rsqrtf(var+1e-5f)*g1[t];
        sc[t]=s; sh[t]=be1[t]-mu*s;
    }
    __syncthreads();
    int n = blockIdx.x*TPB + t;
    if (n >= N) return;
    float v[16];
    const float4* ip = (const float4*)(out_ht + (size_t)n*16);
    #pragma unroll
    for (int q=0;q<4;q++){
        float4 vv = ip[q];
        v[4*q+0]=vv.x*sc[4*q+0]+sh[4*q+0];
        v[4*q+1]=vv.y*sc[4*q+1]+sh[4*q+1];
        v[4*q+2]=vv.z*sc[4*q+2]+sh[4*q+2];
        v[4*q+3]=vv.w*sc[4*q+3]+sh[4*q+3];
    }
    float dv = rsqrtf((float)(cnt[n]+1));
    float o[8];
    #pragma unroll
    for (int k=0;k<8;k++){
        float acc=0.f;
        #pragma unroll
        for (int j=0;j<16;j++) acc = fmaf(v[j], Wg[j*8+k], acc);
        o[k]=acc*dv;
    }
    u32 w0 = (u32)bf16_rne(o[0]) | ((u32)bf16_rne(o[1])<<16);
    u32 w1 = (u32)bf16_rne(o[2]) | ((u32)bf16_rne(o[3])<<16);
    u32 w2 = (u32)bf16_rne(o[4]) | ((u32)bf16_rne(o[5])<<16);
    u32 w3 = (u32)bf16_rne(o[6]) | ((u32)bf16_rne(o[7])<<16);
    xws[n] = make_uint4(w0,w1,w2,w3);
    dinv[n] = dv;
}

// ---------------- K_gcn: gather + fused BN2 partials (no fence) ----------------
__global__ __launch_bounds__(TPB) void k_gcn(
    const int* __restrict__ rowptr, const int* __restrict__ cnt, const int* __restrict__ csr_src,
    const float* __restrict__ dinv, const uint4* __restrict__ xws,
    const float* __restrict__ b_gcn, float* __restrict__ gout, float* __restrict__ part, int N, int cpx)
{
    __shared__ float ls[16][16];
    int bid = blockIdx.x;
    int bid2 = (bid & 7)*cpx + (bid >> 3);
    int t = threadIdx.x;
    int node = bid2*16 + (t >> 4);
    int sub  = t & 15;
    int grp  = t >> 4;
    float val[8];
    #pragma unroll
    for (int k=0;k<8;k++) val[k]=0.f;
    if (node < N){
        int rs = rowptr[node], re = rs + cnt[node];
        float a0=0.f,a1=0.f,a2=0.f,a3=0.f,a4=0.f,a5=0.f,a6=0.f,a7=0.f;
        for (int j=rs+sub; j<re; j+=16){
            int s = csr_src[j];
            uint4 r = xws[s];
            a0 += bf_lo(r.x); a1 += bf_hi(r.x);
            a2 += bf_lo(r.y); a3 += bf_hi(r.y);
            a4 += bf_lo(r.z); a5 += bf_hi(r.z);
            a6 += bf_lo(r.w); a7 += bf_hi(r.w);
        }
        #pragma unroll
        for (int off=1; off<16; off<<=1){
            a0 += __shfl_xor(a0, off); a1 += __shfl_xor(a1, off);
            a2 += __shfl_xor(a2, off); a3 += __shfl_xor(a3, off);
            a4 += __shfl_xor(a4, off); a5 += __shfl_xor(a5, off);
            a6 += __shfl_xor(a6, off); a7 += __shfl_xor(a7, off);
        }
        if (sub == 0){
            uint4 r = xws[node];
            a0 += bf_lo(r.x); a1 += bf_hi(r.x);
            a2 += bf_lo(r.y); a3 += bf_hi(r.y);
            a4 += bf_lo(r.z); a5 += bf_hi(r.z);
            a6 += bf_lo(r.w); a7 += bf_hi(r.w);
            float dd = dinv[node];
            val[0]=fmaf(dd,a0,b_gcn[0]); val[1]=fmaf(dd,a1,b_gcn[1]);
            val[2]=fmaf(dd,a2,b_gcn[2]); val[3]=fmaf(dd,a3,b_gcn[3]);
            val[4]=fmaf(dd,a4,b_gcn[4]); val[5]=fmaf(dd,a5,b_gcn[5]);
            val[6]=fmaf(dd,a6,b_gcn[6]); val[7]=fmaf(dd,a7,b_gcn[7]);
            float4* op = (float4*)(gout + (size_t)node*8);
            op[0] = make_float4(val[0],val[1],val[2],val[3]);
            op[1] = make_float4(val[4],val[5],val[6],val[7]);
        }
    }
    if (sub == 0){
        #pragma unroll
        for (int k=0;k<8;k++){ ls[grp][k] = val[k]; ls[grp][8+k] = val[k]*val[k]; }
    }
    __syncthreads();
    if (t < 16){
        float s = 0.f;
        #pragma unroll
        for (int g2=0; g2<16; g2++) s += ls[g2][t];
        part[(size_t)bid*16 + t] = s;
    }
}

// ---------------- K8: inline BN2 finish (64x16 reduce) + BN2 apply + per-graph dense head ----------------
__global__ __launch_bounds__(TPB) void k8_head(
    const float* __restrict__ gcn, const float* __restrict__ part2,
    const float* __restrict__ g2, const float* __restrict__ be2,
    const float* __restrict__ W1, const float* __restrict__ b1,
    const float* __restrict__ W2, const float* __restrict__ b2,
    const float* __restrict__ Wt, const float* __restrict__ bt,
    const float* __restrict__ Wmu, const float* __restrict__ bmu,
    const float* __restrict__ Wls, const float* __restrict__ bls,
    float* __restrict__ out, int N, int B)
{
    __shared__ float v[4096];
    __shared__ float red[8][32];
    __shared__ float ls8[16][16];
    __shared__ float bnv[16];
    __shared__ float y1[32], y2[16], y3[64];
    int b = blockIdx.x, t = threadIdx.x;
    {
        int col = t & 15, grp = t >> 4;
        float s = 0.f;
        #pragma unroll
        for (int i=0;i<4;i++) s += part2[(size_t)(grp + 16*i)*16 + col];
        ls8[grp][col] = s;
    }
    __syncthreads();
    if (t < 16){
        float a = 0.f;
        #pragma unroll
        for (int g=0; g<16; g++) a += ls8[g][t];
        bnv[t] = a;
    }
    __syncthreads();
    float sc[8], sh[8];
    #pragma unroll
    for (int k=0;k<8;k++){
        float mu  = bnv[k]/(float)N;
        float var = bnv[8+k]/(float)N - mu*mu;
        float s = rsqrtf(var+1e-5f)*g2[k];
        sc[k]=s; sh[k]=be2[k]-mu*s;
    }
    const float* src = gcn + (size_t)b*4096;
    for (int i=t;i<4096;i+=TPB){ int k=i&7; v[i]=src[i]*sc[k]+sh[k]; }
    __syncthreads();
    int j = t & 31, c = t >> 5;
    float p = 0.f;
    int base = c*512;
    for (int i=0;i<512;i++) p = fmaf(v[base+i], W1[(size_t)(base+i)*32+j], p);
    red[c][j] = p;
    __syncthreads();
    if (t < 32){
        float a = b1[t];
        #pragma unroll
        for (int cc=0;cc<8;cc++) a += red[cc][t];
        y1[t] = lrelu(a, 0.01f);
    }
    __syncthreads();
    if (t < 16){
        float a = b2[t];
        #pragma unroll
        for (int i=0;i<32;i++) a = fmaf(y1[i], W2[i*16+t], a);
        y2[t] = lrelu(a, 0.01f);
    }
    __syncthreads();
    if (t < 64){
        float a = bt[t];
        #pragma unroll
        for (int i=0;i<16;i++) a = fmaf(y2[i], Wt[i*64+t], a);
        y3[t] = lrelu(a, 0.01f);
    }
    __syncthreads();
    if (t < 64){
        float amu = bmu[t], als = bls[t];
        #pragma unroll
        for (int i=0;i<64;i++){ amu = fmaf(y3[i], Wmu[i*64+t], amu); als = fmaf(y3[i], Wls[i*64+t], als); }
        out[(size_t)b*64 + t] = amu;
        out[(size_t)B*64 + (size_t)b*64 + t] = als;
    }
}

extern "C" void kernel_launch(void* const* d_in, const int* in_sizes, int n_in,
                              void* d_out, int out_size, void* d_ws, size_t ws_size,
                              hipStream_t stream)
{
    const float* x     = (const float*)d_in[0];
    const int*   ei    = (const int*)  d_in[1];
    const float* W_gat = (const float*)d_in[2];
    const float* atts  = (const float*)d_in[3];
    const float* attd  = (const float*)d_in[4];
    const float* b_gat = (const float*)d_in[5];
    const float* W_ht  = (const float*)d_in[6];
    const float* b_ht  = (const float*)d_in[7];
    const float* g1    = (const float*)d_in[8];
    const float* be1   = (const float*)d_in[9];
    const float* W_gcn = (const float*)d_in[10];
    const float* b_gcn = (const float*)d_in[11];
    const float* g2    = (const float*)d_in[12];
    const float* be2   = (const float*)d_in[13];
    const float* W1    = (const float*)d_in[14];
    const float* b1    = (const float*)d_in[15];
    const float* W2    = (const float*)d_in[16];
    const float* b2    = (const float*)d_in[17];
    const float* Wt    = (const float*)d_in[18];
    const float* bt    = (const float*)d_in[19];
    const float* Wmu   = (const float*)d_in[20];
    const float* bmu   = (const float*)d_in[21];
    const float* Wls   = (const float*)d_in[22];
    const float* bls   = (const float*)d_in[23];
    float* out = (float*)d_out;

    const int N = in_sizes[0] / 32;
    const int E = in_sizes[1] / 2;
    const int B = N / 512;
    const int NBUCK = N / NPB;
    const int NCB = (E + CHUNK - 1) / CHUNK;

    char* wsb = (char*)d_ws;
    size_t off = 0;
    auto alloc = [&](size_t bytes){ void* p = wsb + off; off += (bytes + 255) & ~(size_t)255; return p; };
    char*   hreg    = (char*)  alloc((size_t)N*128);     // merged node rows; later xws+gout
    float*  out_ht  = (float*) alloc((size_t)N*16*4);
    float*  dinv    = (float*) alloc((size_t)N*4);
    int*    cnt     = (int*)   alloc((size_t)N*4);
    int*    rowptr  = (int*)   alloc((size_t)N*4);
    float*  part    = (float*) alloc((size_t)(N/4)*32*4);  // gat partials (N/4 rows x 32)
    float*  part2   = (float*) alloc(8192*4);
    int*    csr_src = (int*)   alloc((size_t)E*4);
    u32*    staging = (u32*)   alloc((size_t)NCB*CHUNK*4);
    int*    chunk_off = (int*) alloc((size_t)NCB*256*4);
    int*    chunk_cnt = (int*) alloc((size_t)NCB*256*4);
    int*    btot_pad  = (int*) alloc((size_t)NBUCK*16*4);
    u32*    hrow    = (u32*)hreg;
    uint4*  xws     = (uint4*)hreg;                       // reuse after k_gat
    float*  gout    = (float*)(hreg + (size_t)N*16);

    hipMemsetAsync(btot_pad, 0, (size_t)NBUCK*16*4, stream);

    dim3 tb(TPB);
    dim3 tbb(TPB_BIN);
    int gbN = (N+TPB-1)/TPB;
    int nbGat = N/4;          // divisible by 8
    int nbGcn = N/16;         // divisible by 8

    k_bin1   <<<NCB,   tbb, 0, stream>>>(ei, staging, chunk_off, chunk_cnt, btot_pad, E);
    k_bin2   <<<NBUCK, tbb, 0, stream>>>(staging, chunk_off, chunk_cnt, btot_pad, rowptr, cnt, csr_src, NCB);
    k1_embed <<<gbN,   tb, 0, stream>>>(x, W_gat, atts, attd, hrow, N);
    k_gat    <<<nbGat, tb, 0, stream>>>(rowptr, cnt, csr_src, hrow,
                                        b_gat, W_ht, b_ht, out_ht, part, N, nbGat/8);
    k_bnmid16 <<<256,  tb, 0, stream>>>(part, part2);
    k5_bn1_gcnmm<<<gbN, tb, 0, stream>>>(out_ht, part2, g1, be1, W_gcn, cnt, dinv, xws, N);
    k_gcn    <<<nbGcn, tb, 0, stream>>>(rowptr, cnt, csr_src, dinv, xws, b_gcn, gout, part, N, nbGcn/8);
    k_bnmid8 <<<64,    tb, 0, stream>>>(part, part2);
    k8_head  <<<B,     tb, 0, stream>>>(gout, part2, g2, be2, W1, b1, W2, b2, Wt, bt, Wmu, bmu, Wls, bls, out, N, B);
}

// Round 14
// 204.332 us; speedup vs baseline: 4.2674x; 1.0311x over previous
//
#include <hip/hip_runtime.h>
#include <hip/hip_bf16.h>
#include <cstddef>

#define TPB 256
#define TPB_BIN 1024
#define NPB 512        // nodes per bucket
#define BSH 9          // log2(NPB)
#define CHUNK 8192     // edges per k_bin1 block

typedef unsigned int u32;

__device__ __forceinline__ float lrelu(float v, float s){ return v > 0.f ? v : s*v; }

__device__ __forceinline__ unsigned short bf16_rne(float f){
    u32 u = __float_as_uint(f);
    u += 0x7FFFu + ((u >> 16) & 1u);
    return (unsigned short)(u >> 16);
}
__device__ __forceinline__ float bf_lo(u32 w){ return __uint_as_float(w << 16); }
__device__ __forceinline__ float bf_hi(u32 w){ return __uint_as_float(w & 0xFFFF0000u); }

// ---------------- K1: h = x @ W_gat; merged 128B node row [a_src x3 | pad | h bf16 x48 | a_dst x3 | pad] ----------------
__global__ __launch_bounds__(TPB) void k1_embed(
    const float* __restrict__ x, const float* __restrict__ Wg,
    const float* __restrict__ atts, const float* __restrict__ attd,
    u32* __restrict__ hrow, int N)
{
    __shared__ float Ws[32*48];
    __shared__ float As[48], Ad[48];
    for (int i = threadIdx.x; i < 32*48; i += TPB) Ws[i] = Wg[i];
    if (threadIdx.x < 48){ As[threadIdx.x] = atts[threadIdx.x]; Ad[threadIdx.x] = attd[threadIdx.x]; }
    __syncthreads();
    int n = blockIdx.x*TPB + threadIdx.x;
    if (n >= N) return;
    float xr[32];
    const float4* xp = (const float4*)(x + (size_t)n*32);
    #pragma unroll
    for (int i=0;i<8;i++){ float4 v = xp[i]; xr[4*i+0]=v.x; xr[4*i+1]=v.y; xr[4*i+2]=v.z; xr[4*i+3]=v.w; }
    float hv[48];
    #pragma unroll 4
    for (int j=0;j<48;j++){
        float acc = 0.f;
        #pragma unroll
        for (int i=0;i<32;i++) acc = fmaf(xr[i], Ws[i*48+j], acc);
        hv[j] = acc;
    }
    float asv[3], adv[3];
    #pragma unroll
    for (int hh=0;hh<3;hh++){
        float s0=0.f, s1=0.f;
        #pragma unroll
        for (int d=0;d<16;d++){ s0 = fmaf(hv[hh*16+d], As[hh*16+d], s0); s1 = fmaf(hv[hh*16+d], Ad[hh*16+d], s1); }
        asv[hh]=s0; adv[hh]=s1;
    }
    u32 w[24];
    #pragma unroll
    for (int q=0;q<12;q++){
        w[2*q]   = (u32)bf16_rne(hv[4*q+0]) | ((u32)bf16_rne(hv[4*q+1]) << 16);
        w[2*q+1] = (u32)bf16_rne(hv[4*q+2]) | ((u32)bf16_rne(hv[4*q+3]) << 16);
    }
    uint4* hp4 = (uint4*)(hrow + (size_t)n*32);
    hp4[0] = make_uint4(__float_as_uint(asv[0]), __float_as_uint(asv[1]), __float_as_uint(asv[2]), 0u);
    #pragma unroll
    for (int i=0;i<6;i++) hp4[1+i] = make_uint4(w[4*i],w[4*i+1],w[4*i+2],w[4*i+3]);
    hp4[7] = make_uint4(__float_as_uint(adv[0]), __float_as_uint(adv[1]), __float_as_uint(adv[2]), 0u);
}

// ---------------- k_bin1: chunk -> bucket-grouped block-private staging (1024 threads, wave-scan) ----------------
__global__ __launch_bounds__(TPB_BIN) void k_bin1(
    const int* __restrict__ ei, u32* __restrict__ staging,
    int* __restrict__ chunk_off, int* __restrict__ chunk_cnt,
    int* __restrict__ btot_pad, int E)
{
    __shared__ uint2 stash[CHUNK];
    __shared__ int lcnt[256], lcur[256];
    int t = threadIdx.x;
    int blockStart = blockIdx.x * CHUNK;
    int len = E - blockStart; if (len > CHUNK) len = CHUNK; if (len < 0) len = 0;
    if (t < 256) lcnt[t] = 0;
    __syncthreads();
    for (int i = t; i < len; i += TPB_BIN){
        int s = ei[blockStart + i];
        int d = ei[E + blockStart + i];
        stash[i] = make_uint2((unsigned)s, (unsigned)d);
        atomicAdd(&lcnt[d >> BSH], 1);
    }
    __syncthreads();
    if (t < 256){
        int myc = lcnt[t];
        atomicAdd(&btot_pad[t*16], myc);
        chunk_cnt[blockIdx.x*256 + t] = myc;
    }
    __syncthreads();
    if (t < 64){
        int v0=lcnt[4*t+0], v1=lcnt[4*t+1], v2=lcnt[4*t+2], v3=lcnt[4*t+3];
        int s = v0+v1+v2+v3, tot = s;
        #pragma unroll
        for (int off=1; off<64; off<<=1){ int xch = __shfl_up(s, off); if (t >= off) s += xch; }
        int base = s - tot;
        lcur[4*t+0]=base; lcur[4*t+1]=base+v0; lcur[4*t+2]=base+v0+v1; lcur[4*t+3]=base+v0+v1+v2;
    }
    __syncthreads();
    if (t < 256) chunk_off[blockIdx.x*256 + t] = lcur[t];
    __syncthreads();
    for (int i = t; i < len; i += TPB_BIN){
        uint2 e = stash[i];
        int b = (int)(e.y >> BSH);
        int pos = atomicAdd(&lcur[b], 1);
        staging[blockStart + pos] = e.x | ((e.y & (NPB-1u)) << 17);
    }
}

// ---------------- k_bin2: per-bucket assemble via direct chunk-segment iteration ----------------
__global__ __launch_bounds__(TPB_BIN) void k_bin2(
    const u32* __restrict__ staging,
    const int* __restrict__ chunk_off, const int* __restrict__ chunk_cnt,
    const int* __restrict__ btot_pad, int* __restrict__ rowptr, int* __restrict__ cnt_g,
    int* __restrict__ csr_src, int NCB)
{
    __shared__ int co[256], cl[256];
    __shared__ int lcnt[NPB], lcur[NPB];
    __shared__ int cbs;
    int b = blockIdx.x, t = threadIdx.x;
    if (t < 256){
        co[t] = (t < NCB) ? chunk_off[t*256 + b] : 0;
        cl[t] = (t < NCB) ? chunk_cnt[t*256 + b] : 0;
    }
    if (t < NPB) lcnt[t] = 0;
    if (t < 64){
        int s = 0;
        for (int i=t; i<b; i+=64) s += btot_pad[i*16];
        #pragma unroll
        for (int off=32; off; off>>=1) s += __shfl_xor(s, off);
        if (t == 0) cbs = s;
    }
    __syncthreads();
    int cb = cbs;
    int wv = t >> 6, lane = t & 63;   // 16 waves
    for (int c = wv; c < NCB; c += 16){
        int len = cl[c];
        size_t base = (size_t)c*CHUNK + co[c];
        for (int i = lane; i < len; i += 64){
            u32 val = staging[base + i];
            atomicAdd(&lcnt[(val>>17)&(NPB-1u)], 1);
        }
    }
    __syncthreads();
    if (t < 64){
        int v[8]; int ss = 0;
        #pragma unroll
        for (int k=0;k<8;k++){ v[k] = lcnt[8*t+k]; ss += v[k]; }
        int tot = ss;
        #pragma unroll
        for (int off=1; off<64; off<<=1){ int xch = __shfl_up(ss, off); if (t >= off) ss += xch; }
        int base = ss - tot;
        #pragma unroll
        for (int k=0;k<8;k++){ lcur[8*t+k] = base; base += v[k]; }
    }
    __syncthreads();
    if (t < NPB){ rowptr[b*NPB + t] = cb + lcur[t]; cnt_g[b*NPB + t] = lcnt[t]; }
    __syncthreads();
    for (int c = wv; c < NCB; c += 16){
        int len = cl[c];
        size_t base = (size_t)c*CHUNK + co[c];
        for (int i = lane; i < len; i += 64){
            u32 val = staging[base + i];
            int node = (int)((val>>17)&(NPB-1u));
            int pos = atomicAdd(&lcur[node],1);
            csr_src[cb+pos] = (int)(val & 0x1FFFFu);
        }
    }
}

// ---------------- K_gat: wave/node; R9 masked uniform-trip loop; a_dst from hrow; LDS epilogue; fused BN1 ----------------
__global__ __launch_bounds__(TPB) void k_gat(
    const int* __restrict__ rowptr, const int* __restrict__ cnt, const int* __restrict__ csr_src,
    const u32* __restrict__ hrow,
    const float* __restrict__ b_gat,
    const float* __restrict__ W_ht, const float* __restrict__ b_ht,
    float* __restrict__ out_ht, float* __restrict__ part, int N, int cpx)
{
    __shared__ float Wh[768];
    __shared__ float bg[48], bh[16];
    __shared__ float gl[4][52];
    __shared__ float ls2[4][16];
    for (int i=threadIdx.x;i<768;i+=TPB) Wh[i]=W_ht[i];
    if (threadIdx.x<48) bg[threadIdx.x]=b_gat[threadIdx.x];
    if (threadIdx.x<16) bh[threadIdx.x]=b_ht[threadIdx.x];
    __syncthreads();
    int bid = blockIdx.x;
    int bid2 = (bid & 7)*cpx + (bid >> 3);       // XCD-contiguous swizzle (gridDim % 8 == 0)
    int lane = threadIdx.x & 63;
    int wv = threadIdx.x >> 6;
    int n = bid2*4 + wv;                          // grid = N/4 exactly

    int g = lane>>4, q = lane&15;
    int hq = (q < 12) ? (q >> 2) : (q - 12);
    if (q == 15) hq = 0;
    bool is_msg = (q < 12);
    bool is_z   = (q >= 12 && q < 15);

    float adh   = __uint_as_float(hrow[(size_t)n*32 + 28 + hq]);
    float asn_h = __uint_as_float(hrow[(size_t)n*32 + hq]);
    float wself = __expf(lrelu(asn_h + adh, 0.2f));

    int rs = rowptr[n];
    int deg = cnt[n];

    float4 acc = make_float4(0.f,0.f,0.f,0.f);
    float zacc = 0.f;

    for (int base = 0; base < deg; base += 64){
        int m = deg - base; if (m > 64) m = 64;           // wave-uniform
        int idx = csr_src[rs + base + (lane < m ? lane : 0)];
        int niter = (m + 15) >> 4;                        // wave-uniform trip count
        for (int i = 0; i < niter; i++){
            int jj = g + (i << 4);                        // lanes jj..jj+12 always in [0,63]
            int s0=__shfl(idx,jj), s1=__shfl(idx,jj+4), s2=__shfl(idx,jj+8), s3=__shfl(idx,jj+12);
            const u32* p0 = hrow + (size_t)s0*32;
            const u32* p1 = hrow + (size_t)s1*32;
            const u32* p2 = hrow + (size_t)s2*32;
            const u32* p3 = hrow + (size_t)s3*32;
            float av0=__uint_as_float(p0[hq]);
            float av1=__uint_as_float(p1[hq]);
            float av2=__uint_as_float(p2[hq]);
            float av3=__uint_as_float(p3[hq]);
            uint2 r0,r1,r2,r3;
            if (is_msg){
                r0=*(const uint2*)(p0+4+2*q); r1=*(const uint2*)(p1+4+2*q);
                r2=*(const uint2*)(p2+4+2*q); r3=*(const uint2*)(p3+4+2*q);
            }
            float w0 = (jj      < m) ? __expf(lrelu(av0+adh,0.2f)) : 0.f;
            float w1 = (jj + 4  < m) ? __expf(lrelu(av1+adh,0.2f)) : 0.f;
            float w2 = (jj + 8  < m) ? __expf(lrelu(av2+adh,0.2f)) : 0.f;
            float w3 = (jj + 12 < m) ? __expf(lrelu(av3+adh,0.2f)) : 0.f;
            if (is_msg){
                acc.x=fmaf(w0,bf_lo(r0.x),acc.x); acc.y=fmaf(w0,bf_hi(r0.x),acc.y);
                acc.z=fmaf(w0,bf_lo(r0.y),acc.z); acc.w=fmaf(w0,bf_hi(r0.y),acc.w);
                acc.x=fmaf(w1,bf_lo(r1.x),acc.x); acc.y=fmaf(w1,bf_hi(r1.x),acc.y);
                acc.z=fmaf(w1,bf_lo(r1.y),acc.z); acc.w=fmaf(w1,bf_hi(r1.y),acc.w);
                acc.x=fmaf(w2,bf_lo(r2.x),acc.x); acc.y=fmaf(w2,bf_hi(r2.x),acc.y);
                acc.z=fmaf(w2,bf_lo(r2.y),acc.z); acc.w=fmaf(w2,bf_hi(r2.y),acc.w);
                acc.x=fmaf(w3,bf_lo(r3.x),acc.x); acc.y=fmaf(w3,bf_hi(r3.x),acc.y);
                acc.z=fmaf(w3,bf_lo(r3.y),acc.z); acc.w=fmaf(w3,bf_hi(r3.y),acc.w);
            } else if (is_z){
                zacc += (w0+w1)+(w2+w3);
            }
        }
    }

    #pragma unroll
    for (int off=16; off<64; off<<=1){
        acc.x += __shfl_xor(acc.x, off); acc.y += __shfl_xor(acc.y, off);
        acc.z += __shfl_xor(acc.z, off); acc.w += __shfl_xor(acc.w, off);
        zacc  += __shfl_xor(zacc,  off);
    }
    float z_mine = __shfl(zacc, 12 + hq) + wself;

    if (g==0 && q<12){
        uint2 hs = *(const uint2*)(hrow + (size_t)n*32 + 4 + 2*q);
        float inv = 1.f / z_mine;
        float4 gq;
        gq.x = (acc.x + wself*bf_lo(hs.x))*inv + bg[4*q+0];
        gq.y = (acc.y + wself*bf_hi(hs.x))*inv + bg[4*q+1];
        gq.z = (acc.z + wself*bf_lo(hs.y))*inv + bg[4*q+2];
        gq.w = (acc.w + wself*bf_hi(hs.y))*inv + bg[4*q+3];
        *(float4*)&gl[wv][4*q] = gq;
    }
    __syncthreads();
    int j16 = lane & 15, pr = lane >> 4;
    float oacc = 0.f;
    const float* gv = &gl[wv][pr*12];
    #pragma unroll
    for (int k=0;k<12;k++) oacc = fmaf(gv[k], Wh[(pr*12+k)*16 + j16], oacc);
    oacc += __shfl_xor(oacc, 16);
    oacc += __shfl_xor(oacc, 32);
    float oval = oacc + bh[j16];
    if (lane < 16){
        out_ht[(size_t)n*16 + lane] = oval;
        ls2[wv][lane] = oval;
    }
    __syncthreads();
    int t = threadIdx.x;
    if (t < 16){
        float s=0.f, qd=0.f;
        #pragma unroll
        for (int w2=0;w2<4;w2++){ float v=ls2[w2][t]; s+=v; qd+=v*v; }
        part[(size_t)bid*32 + t] = s;
        part[(size_t)bid*32 + 16 + t] = qd;
    }
}

// mid-reduce 32768 rows x 32 -> 256 rows x 32 (256 blocks, 128 rows each)
__global__ __launch_bounds__(TPB) void k_bnmid16(const float* __restrict__ part, float* __restrict__ part2)
{
    __shared__ float ls[8][32];
    int t = threadIdx.x, b = blockIdx.x;
    int col = t & 31, grp = t >> 5;
    float s = 0.f;
    #pragma unroll
    for (int i=0;i<16;i++){ int r = b*128 + grp*16 + i; s += part[(size_t)r*32 + col]; }
    ls[grp][col] = s; __syncthreads();
    if (t < 32){
        float a = 0.f;
        #pragma unroll
        for (int g=0; g<8; g++) a += ls[g][t];
        part2[(size_t)b*32 + t] = a;
    }
}

// mid-reduce 8192 rows x 16 -> 64 rows x 16 (64 blocks)
__global__ __launch_bounds__(TPB) void k_bnmid8(const float* __restrict__ part, float* __restrict__ part2)
{
    __shared__ float ls[16][16];
    int t = threadIdx.x, b = blockIdx.x;
    int col = t & 15, grp = t >> 4;
    float s = 0.f;
    #pragma unroll
    for (int i=0;i<8;i++){ int r = b*128 + grp + 16*i; s += part[(size_t)r*16 + col]; }
    ls[grp][col] = s; __syncthreads();
    if (t < 16){
        float a = 0.f;
        #pragma unroll
        for (int g=0; g<16; g++) a += ls[g][t];
        part2[(size_t)b*16 + t] = a;
    }
}

// ---------------- K5: inline BN1 finish (256x32 reduce) + BN1 apply + GCN matmul + bf16 xws ----------------
__global__ __launch_bounds__(TPB) void k5_bn1_gcnmm(
    const float* __restrict__ out_ht, const float* __restrict__ part2,
    const float* __restrict__ g1, const float* __restrict__ be1,
    const float* __restrict__ W_gcn, const int* __restrict__ cnt,
    float* __restrict__ dinv, uint4* __restrict__ xws, int N)
{
    __shared__ float ls[8][32];
    __shared__ float bnv[32];
    __shared__ float sc[16], sh[16], Wg[128];
    int t = threadIdx.x;
    {
        int col = t & 31, grp = t >> 5;
        float s = 0.f;
        #pragma unroll
        for (int i=0;i<32;i++) s += part2[(size_t)(grp + 8*i)*32 + col];
        ls[grp][col] = s;
    }
    if (t < 128) Wg[t] = W_gcn[t];
    __syncthreads();
    if (t < 32){
        float a = 0.f;
        #pragma unroll
        for (int g=0; g<8; g++) a += ls[g][t];
        bnv[t] = a;
    }
    __syncthreads();
    if (t < 16){
        float mu  = bnv[t]/(float)N;
        float var = bnv[16+t]/(float)N - mu*mu;
        float s = rsqrtf(var+1e-5f)*g1[t];
        sc[t]=s; sh[t]=be1[t]-mu*s;
    }
    __syncthreads();
    int n = blockIdx.x*TPB + t;
    if (n >= N) return;
    float v[16];
    const float4* ip = (const float4*)(out_ht + (size_t)n*16);
    #pragma unroll
    for (int q=0;q<4;q++){
        float4 vv = ip[q];
        v[4*q+0]=vv.x*sc[4*q+0]+sh[4*q+0];
        v[4*q+1]=vv.y*sc[4*q+1]+sh[4*q+1];
        v[4*q+2]=vv.z*sc[4*q+2]+sh[4*q+2];
        v[4*q+3]=vv.w*sc[4*q+3]+sh[4*q+3];
    }
    float dv = rsqrtf((float)(cnt[n]+1));
    float o[8];
    #pragma unroll
    for (int k=0;k<8;k++){
        float acc=0.f;
        #pragma unroll
        for (int j=0;j<16;j++) acc = fmaf(v[j], Wg[j*8+k], acc);
        o[k]=acc*dv;
    }
    u32 w0 = (u32)bf16_rne(o[0]) | ((u32)bf16_rne(o[1])<<16);
    u32 w1 = (u32)bf16_rne(o[2]) | ((u32)bf16_rne(o[3])<<16);
    u32 w2 = (u32)bf16_rne(o[4]) | ((u32)bf16_rne(o[5])<<16);
    u32 w3 = (u32)bf16_rne(o[6]) | ((u32)bf16_rne(o[7])<<16);
    xws[n] = make_uint4(w0,w1,w2,w3);
    dinv[n] = dv;
}

// ---------------- K_gcn: gather + fused BN2 partials (no fence) ----------------
__global__ __launch_bounds__(TPB) void k_gcn(
    const int* __restrict__ rowptr, const int* __restrict__ cnt, const int* __restrict__ csr_src,
    const float* __restrict__ dinv, const uint4* __restrict__ xws,
    const float* __restrict__ b_gcn, float* __restrict__ gout, float* __restrict__ part, int N, int cpx)
{
    __shared__ float ls[16][16];
    int bid = blockIdx.x;
    int bid2 = (bid & 7)*cpx + (bid >> 3);
    int t = threadIdx.x;
    int node = bid2*16 + (t >> 4);
    int sub  = t & 15;
    int grp  = t >> 4;
    float val[8];
    #pragma unroll
    for (int k=0;k<8;k++) val[k]=0.f;
    if (node < N){
        int rs = rowptr[node], re = rs + cnt[node];
        float a0=0.f,a1=0.f,a2=0.f,a3=0.f,a4=0.f,a5=0.f,a6=0.f,a7=0.f;
        for (int j=rs+sub; j<re; j+=16){
            int s = csr_src[j];
            uint4 r = xws[s];
            a0 += bf_lo(r.x); a1 += bf_hi(r.x);
            a2 += bf_lo(r.y); a3 += bf_hi(r.y);
            a4 += bf_lo(r.z); a5 += bf_hi(r.z);
            a6 += bf_lo(r.w); a7 += bf_hi(r.w);
        }
        #pragma unroll
        for (int off=1; off<16; off<<=1){
            a0 += __shfl_xor(a0, off); a1 += __shfl_xor(a1, off);
            a2 += __shfl_xor(a2, off); a3 += __shfl_xor(a3, off);
            a4 += __shfl_xor(a4, off); a5 += __shfl_xor(a5, off);
            a6 += __shfl_xor(a6, off); a7 += __shfl_xor(a7, off);
        }
        if (sub == 0){
            uint4 r = xws[node];
            a0 += bf_lo(r.x); a1 += bf_hi(r.x);
            a2 += bf_lo(r.y); a3 += bf_hi(r.y);
            a4 += bf_lo(r.z); a5 += bf_hi(r.z);
            a6 += bf_lo(r.w); a7 += bf_hi(r.w);
            float dd = dinv[node];
            val[0]=fmaf(dd,a0,b_gcn[0]); val[1]=fmaf(dd,a1,b_gcn[1]);
            val[2]=fmaf(dd,a2,b_gcn[2]); val[3]=fmaf(dd,a3,b_gcn[3]);
            val[4]=fmaf(dd,a4,b_gcn[4]); val[5]=fmaf(dd,a5,b_gcn[5]);
            val[6]=fmaf(dd,a6,b_gcn[6]); val[7]=fmaf(dd,a7,b_gcn[7]);
            float4* op = (float4*)(gout + (size_t)node*8);
            op[0] = make_float4(val[0],val[1],val[2],val[3]);
            op[1] = make_float4(val[4],val[5],val[6],val[7]);
        }
    }
    if (sub == 0){
        #pragma unroll
        for (int k=0;k<8;k++){ ls[grp][k] = val[k]; ls[grp][8+k] = val[k]*val[k]; }
    }
    __syncthreads();
    if (t < 16){
        float s = 0.f;
        #pragma unroll
        for (int g2=0; g2<16; g2++) s += ls[g2][t];
        part[(size_t)bid*16 + t] = s;
    }
}

// ---------------- K8: inline BN2 finish (64x16 reduce) + BN2 apply + per-graph dense head ----------------
__global__ __launch_bounds__(TPB) void k8_head(
    const float* __restrict__ gcn, const float* __restrict__ part2,
    const float* __restrict__ g2, const float* __restrict__ be2,
    const float* __restrict__ W1, const float* __restrict__ b1,
    const float* __restrict__ W2, const float* __restrict__ b2,
    const float* __restrict__ Wt, const float* __restrict__ bt,
    const float* __restrict__ Wmu, const float* __restrict__ bmu,
    const float* __restrict__ Wls, const float* __restrict__ bls,
    float* __restrict__ out, int N, int B)
{
    __shared__ float v[4096];
    __shared__ float red[8][32];
    __shared__ float ls8[16][16];
    __shared__ float bnv[16];
    __shared__ float y1[32], y2[16], y3[64];
    int b = blockIdx.x, t = threadIdx.x;
    {
        int col = t & 15, grp = t >> 4;
        float s = 0.f;
        #pragma unroll
        for (int i=0;i<4;i++) s += part2[(size_t)(grp + 16*i)*16 + col];
        ls8[grp][col] = s;
    }
    __syncthreads();
    if (t < 16){
        float a = 0.f;
        #pragma unroll
        for (int g=0; g<16; g++) a += ls8[g][t];
        bnv[t] = a;
    }
    __syncthreads();
    float sc[8], sh[8];
    #pragma unroll
    for (int k=0;k<8;k++){
        float mu  = bnv[k]/(float)N;
        float var = bnv[8+k]/(float)N - mu*mu;
        float s = rsqrtf(var+1e-5f)*g2[k];
        sc[k]=s; sh[k]=be2[k]-mu*s;
    }
    const float* src = gcn + (size_t)b*4096;
    for (int i=t;i<4096;i+=TPB){ int k=i&7; v[i]=src[i]*sc[k]+sh[k]; }
    __syncthreads();
    int j = t & 31, c = t >> 5;
    float p = 0.f;
    int base = c*512;
    for (int i=0;i<512;i++) p = fmaf(v[base+i], W1[(size_t)(base+i)*32+j], p);
    red[c][j] = p;
    __syncthreads();
    if (t < 32){
        float a = b1[t];
        #pragma unroll
        for (int cc=0;cc<8;cc++) a += red[cc][t];
        y1[t] = lrelu(a, 0.01f);
    }
    __syncthreads();
    if (t < 16){
        float a = b2[t];
        #pragma unroll
        for (int i=0;i<32;i++) a = fmaf(y1[i], W2[i*16+t], a);
        y2[t] = lrelu(a, 0.01f);
    }
    __syncthreads();
    if (t < 64){
        float a = bt[t];
        #pragma unroll
        for (int i=0;i<16;i++) a = fmaf(y2[i], Wt[i*64+t], a);
        y3[t] = lrelu(a, 0.01f);
    }
    __syncthreads();
    if (t < 64){
        float amu = bmu[t], als = bls[t];
        #pragma unroll
        for (int i=0;i<64;i++){ amu = fmaf(y3[i], Wmu[i*64+t], amu); als = fmaf(y3[i], Wls[i*64+t], als); }
        out[(size_t)b*64 + t] = amu;
        out[(size_t)B*64 + (size_t)b*64 + t] = als;
    }
}

extern "C" void kernel_launch(void* const* d_in, const int* in_sizes, int n_in,
                              void* d_out, int out_size, void* d_ws, size_t ws_size,
                              hipStream_t stream)
{
    const float* x     = (const float*)d_in[0];
    const int*   ei    = (const int*)  d_in[1];
    const float* W_gat = (const float*)d_in[2];
    const float* atts  = (const float*)d_in[3];
    const float* attd  = (const float*)d_in[4];
    const float* b_gat = (const float*)d_in[5];
    const float* W_ht  = (const float*)d_in[6];
    const float* b_ht  = (const float*)d_in[7];
    const float* g1    = (const float*)d_in[8];
    const float* be1   = (const float*)d_in[9];
    const float* W_gcn = (const float*)d_in[10];
    const float* b_gcn = (const float*)d_in[11];
    const float* g2    = (const float*)d_in[12];
    const float* be2   = (const float*)d_in[13];
    const float* W1    = (const float*)d_in[14];
    const float* b1    = (const float*)d_in[15];
    const float* W2    = (const float*)d_in[16];
    const float* b2    = (const float*)d_in[17];
    const float* Wt    = (const float*)d_in[18];
    const float* bt    = (const float*)d_in[19];
    const float* Wmu   = (const float*)d_in[20];
    const float* bmu   = (const float*)d_in[21];
    const float* Wls   = (const float*)d_in[22];
    const float* bls   = (const float*)d_in[23];
    float* out = (float*)d_out;

    const int N = in_sizes[0] / 32;
    const int E = in_sizes[1] / 2;
    const int B = N / 512;
    const int NBUCK = N / NPB;
    const int NCB = (E + CHUNK - 1) / CHUNK;

    char* wsb = (char*)d_ws;
    size_t off = 0;
    auto alloc = [&](size_t bytes){ void* p = wsb + off; off += (bytes + 255) & ~(size_t)255; return p; };
    char*   hreg    = (char*)  alloc((size_t)N*128);     // merged node rows; later xws+gout
    float*  out_ht  = (float*) alloc((size_t)N*16*4);
    float*  dinv    = (float*) alloc((size_t)N*4);
    int*    cnt     = (int*)   alloc((size_t)N*4);
    int*    rowptr  = (int*)   alloc((size_t)N*4);
    float*  part    = (float*) alloc((size_t)(N/4)*32*4);  // gat partials (N/4 rows x 32)
    float*  part2   = (float*) alloc(8192*4);
    int*    csr_src = (int*)   alloc((size_t)E*4);
    u32*    staging = (u32*)   alloc((size_t)NCB*CHUNK*4);
    int*    chunk_off = (int*) alloc((size_t)NCB*256*4);
    int*    chunk_cnt = (int*) alloc((size_t)NCB*256*4);
    int*    btot_pad  = (int*) alloc((size_t)NBUCK*16*4);
    u32*    hrow    = (u32*)hreg;
    uint4*  xws     = (uint4*)hreg;                       // reuse after k_gat
    float*  gout    = (float*)(hreg + (size_t)N*16);

    hipMemsetAsync(btot_pad, 0, (size_t)NBUCK*16*4, stream);

    dim3 tb(TPB);
    dim3 tbb(TPB_BIN);
    int gbN = (N+TPB-1)/TPB;
    int nbGat = N/4;          // divisible by 8
    int nbGcn = N/16;         // divisible by 8

    k_bin1   <<<NCB,   tbb, 0, stream>>>(ei, staging, chunk_off, chunk_cnt, btot_pad, E);
    k_bin2   <<<NBUCK, tbb, 0, stream>>>(staging, chunk_off, chunk_cnt, btot_pad, rowptr, cnt, csr_src, NCB);
    k1_embed <<<gbN,   tb, 0, stream>>>(x, W_gat, atts, attd, hrow, N);
    k_gat    <<<nbGat, tb, 0, stream>>>(rowptr, cnt, csr_src, hrow,
                                        b_gat, W_ht, b_ht, out_ht, part, N, nbGat/8);
    k_bnmid16 <<<256,  tb, 0, stream>>>(part, part2);
    k5_bn1_gcnmm<<<gbN, tb, 0, stream>>>(out_ht, part2, g1, be1, W_gcn, cnt, dinv, xws, N);
    k_gcn    <<<nbGcn, tb, 0, stream>>>(rowptr, cnt, csr_src, dinv, xws, b_gcn, gout, part, N, nbGcn/8);
    k_bnmid8 <<<64,    tb, 0, stream>>>(part, part2);
    k8_head  <<<B,     tb, 0, stream>>>(gout, part2, g2, be2, W1, b1, W2, b2, Wt, bt, Wmu, bmu, Wls, bls, out, N, B);
}